// Round 1
// baseline (457.481 us; speedup 1.0000x reference)
//
#include <hip/hip_runtime.h>
#include <math.h>

#define DEVFN __device__ __forceinline__

typedef __attribute__((ext_vector_type(4))) float f32x4;
typedef __attribute__((ext_vector_type(8))) __bf16 bf16x8;
typedef __attribute__((ext_vector_type(4))) short short4v;

#define NB   64
#define TXD  1024
#define NHD  512
#define HSZ  512
#define ESZ  300
#define VSZ  32000
#define IPRE (ESZ + NHD)       // 812
#define G4   (4*HSZ)           // 2048
#define IPOST (HSZ + NHD)      // 1024
#define HALFD 512

DEVFN short f2bf(float f) {
  unsigned u = __float_as_uint(f);
  u = (u + 0x7fffu + ((u >> 16) & 1u)) >> 16;
  return (short)u;
}
DEVFN float sigm(float x) { return 1.0f / (1.0f + __expf(-x)); }

// ---------------- embedding + concat with c_prev -> rnn_input [64, 812] ---------
__global__ __launch_bounds__(256)
void embed_concat(const int* __restrict__ yt, const float* __restrict__ embW,
                  const float* __restrict__ c_prev, float* __restrict__ rnn_in)
{
  int i = blockIdx.x * 256 + threadIdx.x;
  if (i >= NB * IPRE) return;
  int n = i / IPRE, c = i - n * IPRE;
  float v;
  if (c < ESZ) v = embW[(size_t)yt[n] * ESZ + c];
  else         v = c_prev[(size_t)n * NHD + (c - ESZ)];
  rnn_in[i] = v;
}

// ---------------- generic f32 GEMM: C[64 x N] = A[64 x K] * B[N x K]^T ----------
// EPI: 0 none; 1 +bias1; 2 +bias1+bias2; 3 relu(x + bias1)
template<int EPI, int BETA>
__global__ __launch_bounds__(256)
void gemm64_nt(const float* __restrict__ A, int lda,
               const float* __restrict__ B, int ldb,
               const float* __restrict__ bias1, const float* __restrict__ bias2,
               float* __restrict__ C, int ldc, int K)
{
  __shared__ float As[64][17];
  __shared__ float Bs[64][17];
  const int tid = threadIdx.x;
  const int tx = tid & 15, ty = tid >> 4;
  const int n0 = blockIdx.x * 64;
  const int row = tid >> 2, kq = (tid & 3) * 4;
  float acc[4][4] = {};
  for (int k0 = 0; k0 < K; k0 += 16) {
    float4 av, bv;
    const float* ap = A + (size_t)row * lda;
    const float* bp = B + (size_t)(n0 + row) * ldb;
    if (k0 + kq + 4 <= K) {
      av = *(const float4*)(ap + k0 + kq);
      bv = *(const float4*)(bp + k0 + kq);
    } else {
      av.x = (k0+kq+0 < K) ? ap[k0+kq+0] : 0.f;
      av.y = (k0+kq+1 < K) ? ap[k0+kq+1] : 0.f;
      av.z = (k0+kq+2 < K) ? ap[k0+kq+2] : 0.f;
      av.w = (k0+kq+3 < K) ? ap[k0+kq+3] : 0.f;
      bv.x = (k0+kq+0 < K) ? bp[k0+kq+0] : 0.f;
      bv.y = (k0+kq+1 < K) ? bp[k0+kq+1] : 0.f;
      bv.z = (k0+kq+2 < K) ? bp[k0+kq+2] : 0.f;
      bv.w = (k0+kq+3 < K) ? bp[k0+kq+3] : 0.f;
    }
    __syncthreads();   // previous tile fully consumed
    As[row][kq+0] = av.x; As[row][kq+1] = av.y; As[row][kq+2] = av.z; As[row][kq+3] = av.w;
    Bs[row][kq+0] = bv.x; Bs[row][kq+1] = bv.y; Bs[row][kq+2] = bv.z; Bs[row][kq+3] = bv.w;
    __syncthreads();
    #pragma unroll
    for (int kk = 0; kk < 16; ++kk) {
      float a[4], b[4];
      #pragma unroll
      for (int i = 0; i < 4; ++i) a[i] = As[ty*4+i][kk];
      #pragma unroll
      for (int j = 0; j < 4; ++j) b[j] = Bs[tx*4+j][kk];
      #pragma unroll
      for (int i = 0; i < 4; ++i)
        #pragma unroll
        for (int j = 0; j < 4; ++j)
          acc[i][j] = fmaf(a[i], b[j], acc[i][j]);
    }
  }
  #pragma unroll
  for (int i = 0; i < 4; ++i) {
    int m = ty*4 + i;
    #pragma unroll
    for (int j = 0; j < 4; ++j) {
      int nn = n0 + tx*4 + j;
      float v = acc[i][j];
      if (BETA) v += C[(size_t)m * ldc + nn];
      if (EPI == 1) v += bias1[nn];
      if (EPI == 2) v += bias1[nn] + bias2[nn];
      if (EPI == 3) v = fmaxf(v + bias1[nn], 0.f);
      C[(size_t)m * ldc + nn] = v;
    }
  }
}

// ---------------- LSTM pointwise (PyTorch gate order i,f,g,o) -------------------
__global__ __launch_bounds__(256)
void lstm_point(const float* __restrict__ gates, const float* __restrict__ c_old,
                float* __restrict__ h_new, float* __restrict__ c_new)
{
  int i = blockIdx.x * 256 + threadIdx.x;   // < 64*512
  int n = i >> 9, k = i & 511;
  const float* g = gates + (size_t)n * G4;
  float gi = g[k], gf = g[HSZ + k], gc = g[2*HSZ + k], go = g[3*HSZ + k];
  float c = sigm(gf) * c_old[i] + sigm(gi) * tanhf(gc);
  float h = sigm(go) * tanhf(c);
  h_new[i] = h; c_new[i] = c;
}

// ---------------- attention scores: bf16 MFMA, fused relu+W2 reduction ----------
// scores_part[by][r] = sum_{c in half by} W2[c]*relu(enc_row[r]·W1enc[c] + sproj[n][c])
__global__ __launch_bounds__(256)
void att_score(const float* __restrict__ enc, const float* __restrict__ W1,
               const float* __restrict__ W2, const float* __restrict__ sproj,
               float* __restrict__ spart)
{
  __shared__ __align__(16) short As[64][40];
  __shared__ __align__(16) short Bs[256][40];
  __shared__ float red[4][64];
  const int tid = threadIdx.x;
  const int w = tid >> 6, lane = tid & 63;
  const int r0 = blockIdx.x * 64;          // row tile (same n: 1024 % 64 == 0)
  const int n = r0 >> 10;
  const int c0 = blockIdx.y * 256;         // column half

  const f32x4 fzero = {0.f, 0.f, 0.f, 0.f};
  f32x4 acc[4][4];
  #pragma unroll
  for (int mi = 0; mi < 4; ++mi)
    #pragma unroll
    for (int ni = 0; ni < 4; ++ni) acc[mi][ni] = fzero;

  const int lr = tid >> 3;                 // 0..31
  const int kq = (tid & 7) * 4;            // 0..28 step 4

  for (int k0 = 0; k0 < 512; k0 += 32) {
    // stage A: 64 rows x 32 k, f32 -> bf16
    #pragma unroll
    for (int it = 0; it < 2; ++it) {
      int row = lr + it * 32;
      float4 v = *(const float4*)(enc + (size_t)(r0 + row) * 512 + k0 + kq);
      short4v s = { f2bf(v.x), f2bf(v.y), f2bf(v.z), f2bf(v.w) };
      *(short4v*)&As[row][kq] = s;
    }
    // stage B: 256 cols x 32 k from att_W1 enc-part (row stride 1024)
    #pragma unroll
    for (int it = 0; it < 8; ++it) {
      int c = lr + it * 32;
      float4 v = *(const float4*)(W1 + (size_t)(c0 + c) * 1024 + k0 + kq);
      short4v s = { f2bf(v.x), f2bf(v.y), f2bf(v.z), f2bf(v.w) };
      *(short4v*)&Bs[c][kq] = s;
    }
    __syncthreads();
    bf16x8 af[4], bfr[4];
    #pragma unroll
    for (int mi = 0; mi < 4; ++mi)
      af[mi] = *(const bf16x8*)&As[mi*16 + (lane & 15)][(lane >> 4) * 8];
    #pragma unroll
    for (int ni = 0; ni < 4; ++ni)
      bfr[ni] = *(const bf16x8*)&Bs[w*64 + ni*16 + (lane & 15)][(lane >> 4) * 8];
    #pragma unroll
    for (int mi = 0; mi < 4; ++mi)
      #pragma unroll
      for (int ni = 0; ni < 4; ++ni)
        acc[mi][ni] = __builtin_amdgcn_mfma_f32_16x16x32_bf16(af[mi], bfr[ni], acc[mi][ni], 0, 0, 0);
    __syncthreads();
  }

  // epilogue: relu(acc + sproj) * W2, reduce over this wave's 64 columns
  float part[4][4] = {};
  const float* sp = sproj + (size_t)n * HALFD;
  #pragma unroll
  for (int ni = 0; ni < 4; ++ni) {
    int c = c0 + w*64 + ni*16 + (lane & 15);
    float w2 = W2[c];
    float sc = sp[c];
    #pragma unroll
    for (int mi = 0; mi < 4; ++mi)
      #pragma unroll
      for (int r = 0; r < 4; ++r) {
        float v = acc[mi][ni][r] + sc;
        part[mi][r] += fmaxf(v, 0.f) * w2;
      }
  }
  #pragma unroll
  for (int m = 1; m < 16; m <<= 1)
    #pragma unroll
    for (int mi = 0; mi < 4; ++mi)
      #pragma unroll
      for (int r = 0; r < 4; ++r)
        part[mi][r] += __shfl_xor(part[mi][r], m, 64);
  int g = lane >> 4;
  if ((lane & 15) == 0) {
    #pragma unroll
    for (int mi = 0; mi < 4; ++mi)
      #pragma unroll
      for (int r = 0; r < 4; ++r)
        red[w][mi*16 + g*4 + r] = part[mi][r];
  }
  __syncthreads();
  if (tid < 64)
    spart[(size_t)blockIdx.y * (NB*TXD) + r0 + tid] =
        red[0][tid] + red[1][tid] + red[2][tid] + red[3][tid];
}

// ---------------- softmax over Tx -> alphas [64, 1024] --------------------------
__global__ __launch_bounds__(256)
void softmax_tx(const float* __restrict__ spart, float* __restrict__ alphas)
{
  int n = blockIdx.x, tid = threadIdx.x;
  __shared__ float rb[4];
  __shared__ float sb[4];
  float v[4]; float mx = -1e30f;
  #pragma unroll
  for (int i = 0; i < 4; ++i) {
    int t = tid + i*256;
    v[i] = spart[(size_t)n*TXD + t] + spart[(size_t)NB*TXD + (size_t)n*TXD + t];
    mx = fmaxf(mx, v[i]);
  }
  #pragma unroll
  for (int m = 32; m >= 1; m >>= 1) mx = fmaxf(mx, __shfl_xor(mx, m, 64));
  if ((tid & 63) == 0) rb[tid >> 6] = mx;
  __syncthreads();
  mx = fmaxf(fmaxf(rb[0], rb[1]), fmaxf(rb[2], rb[3]));
  float s = 0.f;
  #pragma unroll
  for (int i = 0; i < 4; ++i) { v[i] = __expf(v[i] - mx); s += v[i]; }
  #pragma unroll
  for (int m = 32; m >= 1; m >>= 1) s += __shfl_xor(s, m, 64);
  if ((tid & 63) == 0) sb[tid >> 6] = s;
  __syncthreads();
  s = sb[0] + sb[1] + sb[2] + sb[3];
  float inv = 1.0f / s;
  #pragma unroll
  for (int i = 0; i < 4; ++i) alphas[(size_t)n*TXD + tid + i*256] = v[i] * inv;
}

// ---------------- context partial sums over Tx chunks ---------------------------
__global__ __launch_bounds__(512)
void context_partial(const float* __restrict__ enc, const float* __restrict__ alphas,
                     float* __restrict__ part)
{
  int n = blockIdx.y, chunk = blockIdx.x;
  int c = threadIdx.x;
  __shared__ float al[128];
  if (threadIdx.x < 128) al[threadIdx.x] = alphas[(size_t)n*TXD + chunk*128 + threadIdx.x];
  __syncthreads();
  const float* e = enc + ((size_t)n*TXD + chunk*128) * NHD + c;
  float s = 0.f;
  #pragma unroll 4
  for (int t = 0; t < 128; ++t) s = fmaf(al[t], e[(size_t)t * NHD], s);
  part[((size_t)n*8 + chunk) * NHD + c] = s;
}

// ---------------- reduce context + build spell input ----------------------------
__global__ __launch_bounds__(256)
void finalize_context(const float* __restrict__ part, const float* __restrict__ h0out,
                      float* __restrict__ ctx_out, float* __restrict__ spell)
{
  int i = blockIdx.x * 256 + threadIdx.x;   // < 64*512
  int n = i >> 9, c = i & 511;
  float s = 0.f;
  #pragma unroll
  for (int j = 0; j < 8; ++j) s += part[((size_t)n*8 + j) * NHD + c];
  ctx_out[i] = s;
  spell[(size_t)n * IPOST + c] = h0out[i];
  spell[(size_t)n * IPOST + HSZ + c] = s;
}

// ---------------- BN train-mode stats -> scale/shift ----------------------------
__global__ __launch_bounds__(256)
void bn_stats(const float* __restrict__ z, const float* __restrict__ gamma,
              const float* __restrict__ beta, float* __restrict__ scale,
              float* __restrict__ shift)
{
  int v = blockIdx.x * 256 + threadIdx.x;
  if (v >= VSZ) return;
  float s = 0.f, s2 = 0.f;
  #pragma unroll 4
  for (int n = 0; n < NB; ++n) {
    float x = z[(size_t)n * VSZ + v];
    s += x; s2 = fmaf(x, x, s2);
  }
  float mean = s * (1.0f / NB);
  float var = s2 * (1.0f / NB) - mean * mean;
  float r = rsqrtf(var + 1e-5f);
  float sc = gamma[v] * r;
  scale[v] = sc;
  shift[v] = beta[v] - mean * sc;
}

// ---------------- final softmax over V (BN applied on the fly) ------------------
__global__ __launch_bounds__(1024)
void softmax_v(const float* __restrict__ z, const float* __restrict__ scale,
               const float* __restrict__ shift, float* __restrict__ out)
{
  int n = blockIdx.x, tid = threadIdx.x;
  const float* zr = z + (size_t)n * VSZ;
  float* orow = out + (size_t)n * VSZ;
  __shared__ float rb[16];
  float mx = -1e30f;
  for (int j = tid; j < VSZ; j += 1024) mx = fmaxf(mx, fmaf(zr[j], scale[j], shift[j]));
  #pragma unroll
  for (int m = 32; m >= 1; m >>= 1) mx = fmaxf(mx, __shfl_xor(mx, m, 64));
  if ((tid & 63) == 0) rb[tid >> 6] = mx;
  __syncthreads();
  #pragma unroll
  for (int i = 0; i < 16; ++i) mx = fmaxf(mx, rb[i]);
  __syncthreads();
  float s = 0.f;
  for (int j = tid; j < VSZ; j += 1024) s += __expf(fmaf(zr[j], scale[j], shift[j]) - mx);
  #pragma unroll
  for (int m = 32; m >= 1; m >>= 1) s += __shfl_xor(s, m, 64);
  if ((tid & 63) == 0) rb[tid >> 6] = s;
  __syncthreads();
  s = 0.f;
  #pragma unroll
  for (int i = 0; i < 16; ++i) s += rb[i];
  float inv = 1.0f / s;
  for (int j = tid; j < VSZ; j += 1024)
    orow[j] = __expf(fmaf(zr[j], scale[j], shift[j]) - mx) * inv;
}

// =================================================================================
extern "C" void kernel_launch(void* const* d_in, const int* in_sizes, int n_in,
                              void* d_out, int out_size, void* d_ws, size_t ws_size,
                              hipStream_t stream)
{
  const int*   yt       = (const int*)  d_in[0];
  const float* h0       = (const float*)d_in[1];
  const float* c0       = (const float*)d_in[2];
  const float* h1       = (const float*)d_in[3];
  const float* c1       = (const float*)d_in[4];
  const float* enc      = (const float*)d_in[5];
  const float* c_prev   = (const float*)d_in[6];
  const float* embW     = (const float*)d_in[7];
  const float* pre_Wih  = (const float*)d_in[8];
  const float* pre_Whh  = (const float*)d_in[9];
  const float* pre_bih  = (const float*)d_in[10];
  const float* pre_bhh  = (const float*)d_in[11];
  const float* post_Wih = (const float*)d_in[12];
  const float* post_Whh = (const float*)d_in[13];
  const float* post_bih = (const float*)d_in[14];
  const float* post_bhh = (const float*)d_in[15];
  const float* att_W1   = (const float*)d_in[16];
  const float* att_b1   = (const float*)d_in[17];
  const float* att_W2   = (const float*)d_in[18];
  // d_in[19] = att_b2: constant over Tx -> cancels in softmax, intentionally unused
  const float* mlp_W    = (const float*)d_in[20];
  const float* mlp_b    = (const float*)d_in[21];
  const float* bn_g     = (const float*)d_in[22];
  const float* bn_b     = (const float*)d_in[23];

  float* out   = (float*)d_out;
  float* o_h0  = out + (size_t)NB * VSZ;
  float* o_c0  = o_h0 + NB * HSZ;
  float* o_h1  = o_c0 + NB * HSZ;
  float* o_c1  = o_h1 + NB * HSZ;
  float* o_ctx = o_c1 + NB * HSZ;

  float* ws     = (float*)d_ws;
  float* rnn_in = ws;                          // 64*812
  float* gates  = rnn_in + NB * IPRE;          // 64*2048
  float* sproj  = gates + NB * G4;             // 64*512
  float* spart  = sproj + NB * HALFD;          // 2*65536
  float* alphas = spart + 2 * NB * TXD;        // 64*1024
  float* ctxp   = alphas + NB * TXD;           // 64*8*512
  float* spell  = ctxp + NB * 8 * NHD;         // 64*1024
  float* zbuf   = spell + NB * IPOST;          // 64*32000
  float* bnsc   = zbuf + (size_t)NB * VSZ;     // 32000
  float* bnsh   = bnsc + VSZ;                  // 32000

  // 1. embedding + concat
  embed_concat<<<(NB*IPRE + 255)/256, 256, 0, stream>>>(yt, embW, c_prev, rnn_in);
  // 2. pre-LSTM gates
  gemm64_nt<0,0><<<G4/64, 256, 0, stream>>>(rnn_in, IPRE, pre_Wih, IPRE, nullptr, nullptr, gates, G4, IPRE);
  gemm64_nt<2,1><<<G4/64, 256, 0, stream>>>(h0, HSZ, pre_Whh, HSZ, pre_bih, pre_bhh, gates, G4, HSZ);
  lstm_point<<<NB*HSZ/256, 256, 0, stream>>>(gates, c0, o_h0, o_c0);
  // 3. sproj = s_i @ W1_s^T + b1 (s-half of att_W1)
  gemm64_nt<1,0><<<HALFD/64, 256, 0, stream>>>(o_h0, HSZ, att_W1 + NHD, NHD + HSZ, att_b1, nullptr, sproj, HALFD, HSZ);
  // 4. attention scores (MFMA) + softmax over Tx
  att_score<<<dim3(NB*TXD/64, 2), 256, 0, stream>>>(enc, att_W1, att_W2, sproj, spart);
  softmax_tx<<<NB, 256, 0, stream>>>(spart, alphas);
  // 5. context
  context_partial<<<dim3(8, NB), 512, 0, stream>>>(enc, alphas, ctxp);
  finalize_context<<<NB*NHD/256, 256, 0, stream>>>(ctxp, o_h0, o_ctx, spell);
  // 6. post-LSTM
  gemm64_nt<0,0><<<G4/64, 256, 0, stream>>>(spell, IPOST, post_Wih, IPOST, nullptr, nullptr, gates, G4, IPOST);
  gemm64_nt<2,1><<<G4/64, 256, 0, stream>>>(h1, HSZ, post_Whh, HSZ, post_bih, post_bhh, gates, G4, HSZ);
  lstm_point<<<NB*HSZ/256, 256, 0, stream>>>(gates, c1, o_h1, o_c1);
  // 7. classifier z = relu(h1 @ mlp_W^T + b)
  gemm64_nt<3,0><<<VSZ/64, 256, 0, stream>>>(o_h1, HSZ, mlp_W, HSZ, mlp_b, nullptr, zbuf, VSZ, HSZ);
  // 8. batchnorm (train stats) + softmax over V
  bn_stats<<<(VSZ + 255)/256, 256, 0, stream>>>(zbuf, bn_g, bn_b, bnsc, bnsh);
  softmax_v<<<NB, 1024, 0, stream>>>(zbuf, bnsc, bnsh, out);
}

// Round 2
// 264.564 us; speedup vs baseline: 1.7292x; 1.7292x over previous
//
#include <hip/hip_runtime.h>
#include <math.h>

#define DEVFN __device__ __forceinline__

typedef __attribute__((ext_vector_type(4))) float f32x4;
typedef __attribute__((ext_vector_type(8))) __bf16 bf16x8;
typedef __attribute__((ext_vector_type(8))) short short8v;

#define NB   64
#define TXD  1024
#define NHD  512
#define HSZ  512
#define ESZ  300
#define VSZ  32000
#define G4   (4*HSZ)           // 2048
#define KPRE (ESZ + NHD + HSZ) // 1324 (emb|c_prev|h0)
#define KPOST 1536             // (h0out|ctx|h1)
#define HALFD 512

DEVFN short f2bf(float f) {
  unsigned u = __float_as_uint(f);
  u = (u + 0x7fffu + ((u >> 16) & 1u)) >> 16;
  return (short)u;
}
DEVFN float sigm(float x) { return 1.0f / (1.0f + __expf(-x)); }

DEVFN short8v pack8(float4 a, float4 b) {
  short8v v;
  v[0]=f2bf(a.x); v[1]=f2bf(a.y); v[2]=f2bf(a.z); v[3]=f2bf(a.w);
  v[4]=f2bf(b.x); v[5]=f2bf(b.y); v[6]=f2bf(b.z); v[7]=f2bf(b.w);
  return v;
}
DEVFN float4 ldA4(const float* __restrict__ A, int lda, int row, int k, int Ka) {
  if (k >= Ka) { float4 z = {0.f,0.f,0.f,0.f}; return z; }
  return *(const float4*)(A + (size_t)row * lda + k);
}
DEVFN float4 ldB4(const float* __restrict__ B1, int ldb1, int split,
                  const float* __restrict__ B2, int ldb2, int row, int k, int Ka) {
  if (k >= Ka) { float4 z = {0.f,0.f,0.f,0.f}; return z; }
  if (k < split) return *(const float4*)(B1 + (size_t)row * ldb1 + k);
  return *(const float4*)(B2 + (size_t)row * ldb2 + (k - split));
}

// ---------- build pre-LSTM concat input [emb | c_prev | h0]  (64 x 1324) --------
__global__ __launch_bounds__(256)
void build_pre_cat(const int* __restrict__ yt, const float* __restrict__ embW,
                   const float* __restrict__ c_prev, const float* __restrict__ h0,
                   float* __restrict__ cat)
{
  int i = blockIdx.x * 256 + threadIdx.x;   // < 64*1324
  int n = i / KPRE, c = i - n * KPRE;
  float v;
  if (c < ESZ)            v = embW[(size_t)yt[n] * ESZ + c];
  else if (c < ESZ + NHD) v = c_prev[(size_t)n * NHD + (c - ESZ)];
  else                    v = h0[(size_t)n * HSZ + (c - ESZ - NHD)];
  cat[i] = v;
}

// ---------- generic MFMA GEMM: C[64 x N] = A[64 x K] * B[N x K]^T (bf16) --------
// B rows split across two arrays at `split`. Split-K over blockIdx.y
// (partial written at C + ks*64*ldc). EPI: 0 none, 3 relu(x+bias1).
template<int EPI>
__global__ __launch_bounds__(256)
void mfma_gemm(const float* __restrict__ A, int lda, int Ka,
               const float* __restrict__ B1, int ldb1, int split,
               const float* __restrict__ B2, int ldb2,
               const float* __restrict__ bias1,
               float* __restrict__ C, int ldc, int Kslice)
{
  __shared__ __align__(16) short As[64][40];
  __shared__ __align__(16) short Bs[256][40];
  const int tid = threadIdx.x;
  const int w = tid >> 6, lane = tid & 63;
  const int n0 = blockIdx.x * 256;
  const int ks = blockIdx.y;
  const int kbeg = ks * Kslice;
  const int kend = min(kbeg + Kslice, Ka);
  C += (size_t)ks * 64 * ldc;

  const f32x4 fz = {0.f,0.f,0.f,0.f};
  f32x4 acc[4][4];
  #pragma unroll
  for (int i = 0; i < 4; ++i)
    #pragma unroll
    for (int j = 0; j < 4; ++j) acc[i][j] = fz;

  const int sr  = tid >> 2;        // 0..63
  const int skc = (tid & 3) * 8;   // 0,8,16,24

  for (int k0 = kbeg; k0 < kend; k0 += 32) {
    float4 a0 = ldA4(A, lda, sr, k0 + skc,     Ka);
    float4 a1 = ldA4(A, lda, sr, k0 + skc + 4, Ka);
    float4 b0[4], b1v[4];
    #pragma unroll
    for (int it = 0; it < 4; ++it) {
      int br = n0 + sr + it * 64;
      b0[it]  = ldB4(B1, ldb1, split, B2, ldb2, br, k0 + skc,     Ka);
      b1v[it] = ldB4(B1, ldb1, split, B2, ldb2, br, k0 + skc + 4, Ka);
    }
    __syncthreads();
    *(short8v*)&As[sr][skc] = pack8(a0, a1);
    #pragma unroll
    for (int it = 0; it < 4; ++it)
      *(short8v*)&Bs[sr + it*64][skc] = pack8(b0[it], b1v[it]);
    __syncthreads();
    bf16x8 af[4], bfr[4];
    #pragma unroll
    for (int mi = 0; mi < 4; ++mi)
      af[mi] = *(const bf16x8*)&As[mi*16 + (lane & 15)][(lane >> 4) * 8];
    #pragma unroll
    for (int ni = 0; ni < 4; ++ni)
      bfr[ni] = *(const bf16x8*)&Bs[w*64 + ni*16 + (lane & 15)][(lane >> 4) * 8];
    #pragma unroll
    for (int mi = 0; mi < 4; ++mi)
      #pragma unroll
      for (int ni = 0; ni < 4; ++ni)
        acc[mi][ni] = __builtin_amdgcn_mfma_f32_16x16x32_bf16(af[mi], bfr[ni], acc[mi][ni], 0, 0, 0);
    __syncthreads();
  }

  const int g = lane >> 4, cl = lane & 15;
  #pragma unroll
  for (int ni = 0; ni < 4; ++ni) {
    int n = n0 + w*64 + ni*16 + cl;
    float b = (EPI == 3) ? bias1[n] : 0.f;
    #pragma unroll
    for (int mi = 0; mi < 4; ++mi)
      #pragma unroll
      for (int r = 0; r < 4; ++r) {
        int m = mi*16 + g*4 + r;
        float v = acc[mi][ni][r];
        if (EPI == 3) v = fmaxf(v + b, 0.f);
        C[(size_t)m * ldc + n] = v;
      }
  }
}

// ---------- LSTM pointwise, summing 4 split-K gate partials ---------------------
__global__ __launch_bounds__(256)
void lstm_point2(const float* __restrict__ gp, const float* __restrict__ bih,
                 const float* __restrict__ bhh, const float* __restrict__ c_old,
                 float* __restrict__ h_new, float* __restrict__ c_new)
{
  int i = blockIdx.x * 256 + threadIdx.x;   // < 64*512
  int n = i >> 9, k = i & 511;
  float g[4];
  #pragma unroll
  for (int j = 0; j < 4; ++j) {
    int idx = j * 512 + k;
    float s = bih[idx] + bhh[idx];
    #pragma unroll
    for (int ks = 0; ks < 4; ++ks)
      s += gp[((size_t)ks*64 + n) * G4 + idx];
    g[j] = s;
  }
  float c = sigm(g[1]) * c_old[i] + sigm(g[0]) * tanhf(g[2]);
  float h = sigm(g[3]) * tanhf(c);
  h_new[i] = h; c_new[i] = c;
}

// ---------- attention scores: 128x256 tile MFMA + fused relu*W2 reduction -------
__global__ __launch_bounds__(256)
void att_score(const float* __restrict__ enc, const float* __restrict__ W1,
               const float* __restrict__ W2, const float* __restrict__ sprojp,
               const float* __restrict__ b1, float* __restrict__ spart)
{
  __shared__ __align__(16) short As[128][40];
  __shared__ __align__(16) short Bs[256][40];
  __shared__ float red[2][2][64];
  const int tid = threadIdx.x;
  const int w = tid >> 6, lane = tid & 63;
  const int wr = w >> 1, wc = w & 1;
  const int r0 = blockIdx.x * 128;
  const int c0 = blockIdx.y * 256;
  const int n = r0 >> 10;

  const f32x4 fz = {0.f,0.f,0.f,0.f};
  f32x4 acc[4][8];
  #pragma unroll
  for (int mi = 0; mi < 4; ++mi)
    #pragma unroll
    for (int ni = 0; ni < 8; ++ni) acc[mi][ni] = fz;

  const int ar  = tid >> 1;          // 0..127
  const int akc = (tid & 1) * 16;    // 0 or 16

  for (int k0 = 0; k0 < 512; k0 += 32) {
    const float* ap = enc + (size_t)(r0 + ar) * 512 + k0 + akc;
    float4 a0 = *(const float4*)(ap);
    float4 a1 = *(const float4*)(ap + 4);
    float4 a2 = *(const float4*)(ap + 8);
    float4 a3 = *(const float4*)(ap + 12);
    float4 c4[2][4];
    #pragma unroll
    for (int it = 0; it < 2; ++it) {
      const float* bp = W1 + (size_t)(c0 + ar + it*128) * 1024 + k0 + akc;
      c4[it][0] = *(const float4*)(bp);
      c4[it][1] = *(const float4*)(bp + 4);
      c4[it][2] = *(const float4*)(bp + 8);
      c4[it][3] = *(const float4*)(bp + 12);
    }
    __syncthreads();
    *(short8v*)&As[ar][akc]     = pack8(a0, a1);
    *(short8v*)&As[ar][akc + 8] = pack8(a2, a3);
    #pragma unroll
    for (int it = 0; it < 2; ++it) {
      *(short8v*)&Bs[ar + it*128][akc]     = pack8(c4[it][0], c4[it][1]);
      *(short8v*)&Bs[ar + it*128][akc + 8] = pack8(c4[it][2], c4[it][3]);
    }
    __syncthreads();
    bf16x8 af[4], bfr[8];
    #pragma unroll
    for (int mi = 0; mi < 4; ++mi)
      af[mi] = *(const bf16x8*)&As[wr*64 + mi*16 + (lane & 15)][(lane >> 4) * 8];
    #pragma unroll
    for (int ni = 0; ni < 8; ++ni)
      bfr[ni] = *(const bf16x8*)&Bs[wc*128 + ni*16 + (lane & 15)][(lane >> 4) * 8];
    #pragma unroll
    for (int mi = 0; mi < 4; ++mi)
      #pragma unroll
      for (int ni = 0; ni < 8; ++ni)
        acc[mi][ni] = __builtin_amdgcn_mfma_f32_16x16x32_bf16(af[mi], bfr[ni], acc[mi][ni], 0, 0, 0);
    __syncthreads();
  }

  // relu(acc + sproj + b1) * W2, reduce over this wave's 128 columns
  float part[4][4] = {};
  #pragma unroll
  for (int ni = 0; ni < 8; ++ni) {
    int c = c0 + wc*128 + ni*16 + (lane & 15);
    float spv = b1[c];
    #pragma unroll
    for (int ks = 0; ks < 4; ++ks)
      spv += sprojp[((size_t)ks*64 + n) * HALFD + c];
    float w2 = W2[c];
    #pragma unroll
    for (int mi = 0; mi < 4; ++mi)
      #pragma unroll
      for (int r = 0; r < 4; ++r)
        part[mi][r] += fmaxf(acc[mi][ni][r] + spv, 0.f) * w2;
  }
  #pragma unroll
  for (int m = 1; m < 16; m <<= 1)
    #pragma unroll
    for (int mi = 0; mi < 4; ++mi)
      #pragma unroll
      for (int r = 0; r < 4; ++r)
        part[mi][r] += __shfl_xor(part[mi][r], m, 64);
  int g = lane >> 4;
  if ((lane & 15) == 0) {
    #pragma unroll
    for (int mi = 0; mi < 4; ++mi)
      #pragma unroll
      for (int r = 0; r < 4; ++r)
        red[wr][wc][mi*16 + g*4 + r] = part[mi][r];
  }
  __syncthreads();
  if (tid < 128)
    spart[(size_t)blockIdx.y * (NB*TXD) + r0 + tid] =
        red[tid >> 6][0][tid & 63] + red[tid >> 6][1][tid & 63];
}

// ---------- softmax over Tx -> alphas [64, 1024] --------------------------------
__global__ __launch_bounds__(256)
void softmax_tx(const float* __restrict__ spart, float* __restrict__ alphas)
{
  int n = blockIdx.x, tid = threadIdx.x;
  __shared__ float rb[4];
  __shared__ float sb[4];
  float v[4]; float mx = -1e30f;
  #pragma unroll
  for (int i = 0; i < 4; ++i) {
    int t = tid + i*256;
    v[i] = spart[(size_t)n*TXD + t] + spart[(size_t)NB*TXD + (size_t)n*TXD + t];
    mx = fmaxf(mx, v[i]);
  }
  #pragma unroll
  for (int m = 32; m >= 1; m >>= 1) mx = fmaxf(mx, __shfl_xor(mx, m, 64));
  if ((tid & 63) == 0) rb[tid >> 6] = mx;
  __syncthreads();
  mx = fmaxf(fmaxf(rb[0], rb[1]), fmaxf(rb[2], rb[3]));
  float s = 0.f;
  #pragma unroll
  for (int i = 0; i < 4; ++i) { v[i] = __expf(v[i] - mx); s += v[i]; }
  #pragma unroll
  for (int m = 32; m >= 1; m >>= 1) s += __shfl_xor(s, m, 64);
  if ((tid & 63) == 0) sb[tid >> 6] = s;
  __syncthreads();
  s = sb[0] + sb[1] + sb[2] + sb[3];
  float inv = 1.0f / s;
  #pragma unroll
  for (int i = 0; i < 4; ++i) alphas[(size_t)n*TXD + tid + i*256] = v[i] * inv;
}

// ---------- context partial sums (16 chunks of 64 timesteps) --------------------
__global__ __launch_bounds__(512)
void context_partial(const float* __restrict__ enc, const float* __restrict__ alphas,
                     float* __restrict__ part)
{
  int n = blockIdx.y, chunk = blockIdx.x;
  int c = threadIdx.x;
  __shared__ float al[64];
  if (threadIdx.x < 64) al[threadIdx.x] = alphas[(size_t)n*TXD + chunk*64 + threadIdx.x];
  __syncthreads();
  const float* e = enc + ((size_t)n*TXD + chunk*64) * NHD + c;
  float s = 0.f;
  #pragma unroll 4
  for (int t = 0; t < 64; ++t) s = fmaf(al[t], e[(size_t)t * NHD], s);
  part[((size_t)n*16 + chunk) * NHD + c] = s;
}

// ---------- reduce context + build post concat [h0out | ctx | h1] ---------------
__global__ __launch_bounds__(256)
void finalize_context(const float* __restrict__ part, const float* __restrict__ h0out,
                      const float* __restrict__ h1in,
                      float* __restrict__ ctx_out, float* __restrict__ cat)
{
  int i = blockIdx.x * 256 + threadIdx.x;   // < 64*512
  int n = i >> 9, c = i & 511;
  float s = 0.f;
  #pragma unroll
  for (int j = 0; j < 16; ++j) s += part[((size_t)n*16 + j) * NHD + c];
  ctx_out[i] = s;
  cat[(size_t)n * KPOST + c] = h0out[i];
  cat[(size_t)n * KPOST + HSZ + c] = s;
  cat[(size_t)n * KPOST + 2*HSZ + c] = h1in[i];
}

// ---------- BN train-mode stats -> scale/shift ----------------------------------
__global__ __launch_bounds__(256)
void bn_stats(const float* __restrict__ z, const float* __restrict__ gamma,
              const float* __restrict__ beta, float* __restrict__ scale,
              float* __restrict__ shift)
{
  int v = blockIdx.x * 256 + threadIdx.x;
  if (v >= VSZ) return;
  float s = 0.f, s2 = 0.f;
  #pragma unroll 4
  for (int n = 0; n < NB; ++n) {
    float x = z[(size_t)n * VSZ + v];
    s += x; s2 = fmaf(x, x, s2);
  }
  float mean = s * (1.0f / NB);
  float var = s2 * (1.0f / NB) - mean * mean;
  float r = rsqrtf(var + 1e-5f);
  float sc = gamma[v] * r;
  scale[v] = sc;
  shift[v] = beta[v] - mean * sc;
}

// ---------- final softmax over V (BN applied on the fly) ------------------------
__global__ __launch_bounds__(1024)
void softmax_v(const float* __restrict__ z, const float* __restrict__ scale,
               const float* __restrict__ shift, float* __restrict__ out)
{
  int n = blockIdx.x, tid = threadIdx.x;
  const float* zr = z + (size_t)n * VSZ;
  float* orow = out + (size_t)n * VSZ;
  __shared__ float rb[16];
  float mx = -1e30f;
  for (int j = tid; j < VSZ; j += 1024) mx = fmaxf(mx, fmaf(zr[j], scale[j], shift[j]));
  #pragma unroll
  for (int m = 32; m >= 1; m >>= 1) mx = fmaxf(mx, __shfl_xor(mx, m, 64));
  if ((tid & 63) == 0) rb[tid >> 6] = mx;
  __syncthreads();
  #pragma unroll
  for (int i = 0; i < 16; ++i) mx = fmaxf(mx, rb[i]);
  __syncthreads();
  float s = 0.f;
  for (int j = tid; j < VSZ; j += 1024) s += __expf(fmaf(zr[j], scale[j], shift[j]) - mx);
  #pragma unroll
  for (int m = 32; m >= 1; m >>= 1) s += __shfl_xor(s, m, 64);
  if ((tid & 63) == 0) rb[tid >> 6] = s;
  __syncthreads();
  s = 0.f;
  #pragma unroll
  for (int i = 0; i < 16; ++i) s += rb[i];
  float inv = 1.0f / s;
  for (int j = tid; j < VSZ; j += 1024)
    orow[j] = __expf(fmaf(zr[j], scale[j], shift[j]) - mx) * inv;
}

// =================================================================================
extern "C" void kernel_launch(void* const* d_in, const int* in_sizes, int n_in,
                              void* d_out, int out_size, void* d_ws, size_t ws_size,
                              hipStream_t stream)
{
  const int*   yt       = (const int*)  d_in[0];
  const float* h0       = (const float*)d_in[1];
  const float* c0       = (const float*)d_in[2];
  const float* h1       = (const float*)d_in[3];
  const float* c1       = (const float*)d_in[4];
  const float* enc      = (const float*)d_in[5];
  const float* c_prev   = (const float*)d_in[6];
  const float* embW     = (const float*)d_in[7];
  const float* pre_Wih  = (const float*)d_in[8];
  const float* pre_Whh  = (const float*)d_in[9];
  const float* pre_bih  = (const float*)d_in[10];
  const float* pre_bhh  = (const float*)d_in[11];
  const float* post_Wih = (const float*)d_in[12];
  const float* post_Whh = (const float*)d_in[13];
  const float* post_bih = (const float*)d_in[14];
  const float* post_bhh = (const float*)d_in[15];
  const float* att_W1   = (const float*)d_in[16];
  const float* att_b1   = (const float*)d_in[17];
  const float* att_W2   = (const float*)d_in[18];
  // d_in[19] = att_b2 cancels under softmax over Tx
  const float* mlp_W    = (const float*)d_in[20];
  const float* mlp_b    = (const float*)d_in[21];
  const float* bn_g     = (const float*)d_in[22];
  const float* bn_b     = (const float*)d_in[23];

  float* out   = (float*)d_out;
  float* o_h0  = out + (size_t)NB * VSZ;
  float* o_c0  = o_h0 + NB * HSZ;
  float* o_h1  = o_c0 + NB * HSZ;
  float* o_c1  = o_h1 + NB * HSZ;
  float* o_ctx = o_c1 + NB * HSZ;

  float* ws       = (float*)d_ws;
  float* pre_cat  = ws;                               // 64*1324
  float* gatesp   = pre_cat + NB * KPRE;              // 4*64*2048
  float* sprojp   = gatesp + 4 * NB * G4;             // 4*64*512
  float* spart    = sprojp + 4 * NB * HALFD;          // 2*64*1024
  float* alphas   = spart + 2 * NB * TXD;             // 64*1024
  float* ctxp     = alphas + NB * TXD;                // 64*16*512
  float* post_cat = ctxp + NB * 16 * NHD;             // 64*1536
  float* zbuf     = post_cat + NB * KPOST;            // 64*32000
  float* bnsc     = zbuf + (size_t)NB * VSZ;          // 32000
  float* bnsh     = bnsc + VSZ;                       // 32000

  // 1. pre concat [emb | c_prev | h0]
  build_pre_cat<<<NB*KPRE/256, 256, 0, stream>>>(yt, embW, c_prev, h0, pre_cat);
  // 2. pre gates (fused ih+hh, split-K x4) + LSTM pointwise
  mfma_gemm<0><<<dim3(G4/256, 4), 256, 0, stream>>>(
      pre_cat, KPRE, KPRE, pre_Wih, ESZ + NHD, ESZ + NHD, pre_Whh, HSZ,
      nullptr, gatesp, G4, 352);
  lstm_point2<<<NB*HSZ/256, 256, 0, stream>>>(gatesp, pre_bih, pre_bhh, c0, o_h0, o_c0);
  // 3. sproj partials: s_i @ W1_s^T (split-K x4; bias+reduce fused into att_score)
  mfma_gemm<0><<<dim3(HALFD/256, 4), 256, 0, stream>>>(
      o_h0, HSZ, HSZ, att_W1 + NHD, NHD + HSZ, HSZ, att_W1 + NHD, NHD + HSZ,
      nullptr, sprojp, HALFD, 128);
  // 4. attention scores + softmax over Tx
  att_score<<<dim3(NB*TXD/128, 2), 256, 0, stream>>>(enc, att_W1, att_W2, sprojp, att_b1, spart);
  softmax_tx<<<NB, 256, 0, stream>>>(spart, alphas);
  // 5. context
  context_partial<<<dim3(16, NB), 512, 0, stream>>>(enc, alphas, ctxp);
  finalize_context<<<NB*NHD/256, 256, 0, stream>>>(ctxp, o_h0, h1, o_ctx, post_cat);
  // 6. post gates (fused ih+hh, split-K x4) + LSTM pointwise
  mfma_gemm<0><<<dim3(G4/256, 4), 256, 0, stream>>>(
      post_cat, KPOST, KPOST, post_Wih, HSZ + NHD, HSZ + NHD, post_Whh, HSZ,
      nullptr, gatesp, G4, 384);
  lstm_point2<<<NB*HSZ/256, 256, 0, stream>>>(gatesp, post_bih, post_bhh, c1, o_h1, o_c1);
  // 7. classifier z = relu(h1 @ mlp_W^T + b)
  mfma_gemm<3><<<dim3(VSZ/256, 1), 256, 0, stream>>>(
      o_h1, HSZ, HSZ, mlp_W, HSZ, HSZ, mlp_W, HSZ, mlp_b, zbuf, VSZ, 512);
  // 8. batchnorm (train stats) + softmax over V
  bn_stats<<<(VSZ + 255)/256, 256, 0, stream>>>(zbuf, bn_g, bn_b, bnsc, bnsh);
  softmax_v<<<NB, 1024, 0, stream>>>(zbuf, bnsc, bnsh, out);
}

// Round 3
// 228.155 us; speedup vs baseline: 2.0051x; 1.1596x over previous
//
#include <hip/hip_runtime.h>
#include <math.h>

#define DEVFN __device__ __forceinline__

typedef __attribute__((ext_vector_type(4))) float f32x4;
typedef __attribute__((ext_vector_type(8))) __bf16 bf16x8;
typedef __attribute__((ext_vector_type(4))) short short4v;
typedef __attribute__((ext_vector_type(8))) short short8v;

#define NB   64
#define TXD  1024
#define NHD  512
#define HSZ  512
#define ESZ  300
#define VSZ  32000
#define G4   (4*HSZ)           // 2048
#define KPRE (ESZ + NHD + HSZ) // 1324 (emb|c_prev|h0)
#define KPOST 1536             // (h0out|ctx|h1)
#define HALFD 512

DEVFN short f2bf(float f) {
  unsigned u = __float_as_uint(f);
  u = (u + 0x7fffu + ((u >> 16) & 1u)) >> 16;
  return (short)u;
}
DEVFN float sigm(float x) { return 1.0f / (1.0f + __expf(-x)); }

DEVFN short8v pack8(float4 a, float4 b) {
  short8v v;
  v[0]=f2bf(a.x); v[1]=f2bf(a.y); v[2]=f2bf(a.z); v[3]=f2bf(a.w);
  v[4]=f2bf(b.x); v[5]=f2bf(b.y); v[6]=f2bf(b.z); v[7]=f2bf(b.w);
  return v;
}
DEVFN bf16x8 pack8f(float4 a, float4 b) {
  bf16x8 v;
  v[0]=(__bf16)a.x; v[1]=(__bf16)a.y; v[2]=(__bf16)a.z; v[3]=(__bf16)a.w;
  v[4]=(__bf16)b.x; v[5]=(__bf16)b.y; v[6]=(__bf16)b.z; v[7]=(__bf16)b.w;
  return v;
}
// async global->LDS, 16B per lane: dest = uniform base + lane*16
DEVFN void gload16(const float* g, float* lds_base) {
  __builtin_amdgcn_global_load_lds(
      (const __attribute__((address_space(1))) unsigned int*)g,
      (__attribute__((address_space(3))) unsigned int*)lds_base, 16, 0, 0);
}

DEVFN float4 ldA4(const float* __restrict__ A, int lda, int row, int k, int Ka) {
  if (k >= Ka) { float4 z = {0.f,0.f,0.f,0.f}; return z; }
  return *(const float4*)(A + (size_t)row * lda + k);
}
DEVFN float4 ldB4(const float* __restrict__ B1, int ldb1, int split,
                  const float* __restrict__ B2, int ldb2, int row, int k, int Ka) {
  if (k >= Ka) { float4 z = {0.f,0.f,0.f,0.f}; return z; }
  if (k < split) return *(const float4*)(B1 + (size_t)row * ldb1 + k);
  return *(const float4*)(B2 + (size_t)row * ldb2 + (k - split));
}

// ---------- build pre-LSTM concat input [emb | c_prev | h0]  (64 x 1324) --------
__global__ __launch_bounds__(256)
void build_pre_cat(const int* __restrict__ yt, const float* __restrict__ embW,
                   const float* __restrict__ c_prev, const float* __restrict__ h0,
                   float* __restrict__ cat)
{
  int i = blockIdx.x * 256 + threadIdx.x;   // < 64*1324
  if (i >= NB * KPRE) return;
  int n = i / KPRE, c = i - n * KPRE;
  float v;
  if (c < ESZ)            v = embW[(size_t)yt[n] * ESZ + c];
  else if (c < ESZ + NHD) v = c_prev[(size_t)n * NHD + (c - ESZ)];
  else                    v = h0[(size_t)n * HSZ + (c - ESZ - NHD)];
  cat[i] = v;
}

// ---------- generic MFMA GEMM: C[64 x N] = A[64 x K] * B[N x K]^T (bf16) --------
// Kslice MUST be a multiple of 32. Split-K partial at C + ks*64*ldc.
// EPI: 0 none, 3 relu(x+bias1).
template<int EPI>
__global__ __launch_bounds__(256)
void mfma_gemm(const float* __restrict__ A, int lda, int Ka,
               const float* __restrict__ B1, int ldb1, int split,
               const float* __restrict__ B2, int ldb2,
               const float* __restrict__ bias1,
               float* __restrict__ C, int ldc, int Kslice)
{
  __shared__ __align__(16) short As[64][40];
  __shared__ __align__(16) short Bs[256][40];
  const int tid = threadIdx.x;
  const int w = tid >> 6, lane = tid & 63;
  const int n0 = blockIdx.x * 256;
  const int ks = blockIdx.y;
  const int kbeg = ks * Kslice;
  const int kend = min(kbeg + Kslice, Ka);
  C += (size_t)ks * 64 * ldc;

  const f32x4 fz = {0.f,0.f,0.f,0.f};
  f32x4 acc[4][4];
  #pragma unroll
  for (int i = 0; i < 4; ++i)
    #pragma unroll
    for (int j = 0; j < 4; ++j) acc[i][j] = fz;

  const int sr  = tid >> 2;        // 0..63
  const int skc = (tid & 3) * 8;   // 0,8,16,24

  for (int k0 = kbeg; k0 < kend; k0 += 32) {
    float4 a0 = ldA4(A, lda, sr, k0 + skc,     Ka);
    float4 a1 = ldA4(A, lda, sr, k0 + skc + 4, Ka);
    float4 b0[4], b1v[4];
    #pragma unroll
    for (int it = 0; it < 4; ++it) {
      int br = n0 + sr + it * 64;
      b0[it]  = ldB4(B1, ldb1, split, B2, ldb2, br, k0 + skc,     Ka);
      b1v[it] = ldB4(B1, ldb1, split, B2, ldb2, br, k0 + skc + 4, Ka);
    }
    __syncthreads();
    *(short8v*)&As[sr][skc] = pack8(a0, a1);
    #pragma unroll
    for (int it = 0; it < 4; ++it)
      *(short8v*)&Bs[sr + it*64][skc] = pack8(b0[it], b1v[it]);
    __syncthreads();
    bf16x8 af[4], bfr[4];
    #pragma unroll
    for (int mi = 0; mi < 4; ++mi)
      af[mi] = *(const bf16x8*)&As[mi*16 + (lane & 15)][(lane >> 4) * 8];
    #pragma unroll
    for (int ni = 0; ni < 4; ++ni)
      bfr[ni] = *(const bf16x8*)&Bs[w*64 + ni*16 + (lane & 15)][(lane >> 4) * 8];
    #pragma unroll
    for (int mi = 0; mi < 4; ++mi)
      #pragma unroll
      for (int ni = 0; ni < 4; ++ni)
        acc[mi][ni] = __builtin_amdgcn_mfma_f32_16x16x32_bf16(af[mi], bfr[ni], acc[mi][ni], 0, 0, 0);
    __syncthreads();
  }

  const int g = lane >> 4, cl = lane & 15;
  #pragma unroll
  for (int ni = 0; ni < 4; ++ni) {
    int n = n0 + w*64 + ni*16 + cl;
    float b = (EPI == 3) ? bias1[n] : 0.f;
    #pragma unroll
    for (int mi = 0; mi < 4; ++mi)
      #pragma unroll
      for (int r = 0; r < 4; ++r) {
        int m = mi*16 + g*4 + r;
        float v = acc[mi][ni][r];
        if (EPI == 3) v = fmaxf(v + b, 0.f);
        C[(size_t)m * ldc + n] = v;
      }
  }
}

// ---------- LSTM pointwise, summing np split-K gate partials --------------------
__global__ __launch_bounds__(256)
void lstm_point2(const float* __restrict__ gp, int np,
                 const float* __restrict__ bih, const float* __restrict__ bhh,
                 const float* __restrict__ c_old,
                 float* __restrict__ h_new, float* __restrict__ c_new)
{
  int i = blockIdx.x * 256 + threadIdx.x;   // < 64*512
  int n = i >> 9, k = i & 511;
  float g[4];
  #pragma unroll
  for (int j = 0; j < 4; ++j) {
    int idx = j * 512 + k;
    float s = bih[idx] + bhh[idx];
    for (int ks = 0; ks < np; ++ks)
      s += gp[((size_t)ks*64 + n) * G4 + idx];
    g[j] = s;
  }
  float c = sigm(g[1]) * c_old[i] + sigm(g[0]) * tanhf(g[2]);
  float h = sigm(g[3]) * tanhf(c);
  h_new[i] = h; c_new[i] = c;
}

// ---------- attention scores: m97-style 128x128 tile, global_load_lds + swizzle -
// f32 tiles in LDS (XOR-swizzled), converted to bf16 at fragment build.
// Swizzle: phys_byte = logical_byte ^ ((row&7)<<4), within 256B rows.
__global__ __launch_bounds__(256)
void att_score(const float* __restrict__ enc, const float* __restrict__ W1,
               const float* __restrict__ W2, const float* __restrict__ sprojp,
               const float* __restrict__ b1, float* __restrict__ spart)
{
  __shared__ __align__(16) float As[128][64];   // 32 KB
  __shared__ __align__(16) float Bs[128][64];   // 32 KB
  __shared__ float red[2][2][64];
  const int tid = threadIdx.x;
  const int w = tid >> 6, lane = tid & 63;
  const int wr = w >> 1, wc = w & 1;
  const int r0 = blockIdx.x * 128;          // row tile (1024 rows per n, 128 | 1024)
  const int c0 = blockIdx.y * 128;          // col tile of the 512 hidden units
  const int n = r0 >> 10;
  const int cl = lane & 15, g = lane >> 4;

  const f32x4 fz = {0.f,0.f,0.f,0.f};
  f32x4 acc[4][4];
  #pragma unroll
  for (int mi = 0; mi < 4; ++mi)
    #pragma unroll
    for (int ni = 0; ni < 4; ++ni) acc[mi][ni] = fz;

  // staging: each gload16 covers 4 rows (64 lanes x 16B = 1KB, 256B rows).
  // lane -> row = base + lane/16, phys col byte = (lane&15)*16.
  // pre-swizzled global col (floats): ((lane&15)*16 ^ ((row&7)<<4)) >> 2
  const int lrow = lane >> 4;               // 0..3

  for (int k0 = 0; k0 < 512; k0 += 64) {
    #pragma unroll
    for (int it = 0; it < 8; ++it) {
      int rb = (w << 5) + it * 4;           // wave-uniform row base
      int row = rb + lrow;
      int cf = (((lane & 15) << 4) ^ ((row & 7) << 4)) >> 2;
      gload16(enc + (size_t)(r0 + row) * 512 + k0 + cf, &As[rb][0]);
      gload16(W1 + (size_t)(c0 + row) * 1024 + k0 + cf, &Bs[rb][0]);
    }
    __syncthreads();
    const int m = (cl & 7) << 4;
    #pragma unroll
    for (int h = 0; h < 2; ++h) {
      bf16x8 af[4], bfv[4];
      #pragma unroll
      for (int mi = 0; mi < 4; ++mi) {
        int row = wr*64 + mi*16 + cl;
        const char* base = (const char*)As + (size_t)row*256 + h*128;
        float4 lo = *(const float4*)(base + ((g*32) ^ m));
        float4 hi = *(const float4*)(base + ((g*32 + 16) ^ m));
        af[mi] = pack8f(lo, hi);
      }
      #pragma unroll
      for (int ni = 0; ni < 4; ++ni) {
        int row = wc*64 + ni*16 + cl;
        const char* base = (const char*)Bs + (size_t)row*256 + h*128;
        float4 lo = *(const float4*)(base + ((g*32) ^ m));
        float4 hi = *(const float4*)(base + ((g*32 + 16) ^ m));
        bfv[ni] = pack8f(lo, hi);
      }
      #pragma unroll
      for (int mi = 0; mi < 4; ++mi)
        #pragma unroll
        for (int ni = 0; ni < 4; ++ni)
          acc[mi][ni] = __builtin_amdgcn_mfma_f32_16x16x32_bf16(af[mi], bfv[ni], acc[mi][ni], 0, 0, 0);
    }
    __syncthreads();
  }

  // epilogue: relu(acc + sproj + b1) * W2, reduce over this wave's 64 columns
  float part[4][4] = {};
  #pragma unroll
  for (int ni = 0; ni < 4; ++ni) {
    int c = c0 + wc*64 + ni*16 + cl;
    float spv = b1[c];
    #pragma unroll
    for (int ks = 0; ks < 4; ++ks)
      spv += sprojp[((size_t)ks*64 + n) * HALFD + c];
    float w2 = W2[c];
    #pragma unroll
    for (int mi = 0; mi < 4; ++mi)
      #pragma unroll
      for (int r = 0; r < 4; ++r)
        part[mi][r] += fmaxf(acc[mi][ni][r] + spv, 0.f) * w2;
  }
  #pragma unroll
  for (int mm = 1; mm < 16; mm <<= 1)
    #pragma unroll
    for (int mi = 0; mi < 4; ++mi)
      #pragma unroll
      for (int r = 0; r < 4; ++r)
        part[mi][r] += __shfl_xor(part[mi][r], mm, 64);
  if (cl == 0) {
    #pragma unroll
    for (int mi = 0; mi < 4; ++mi)
      #pragma unroll
      for (int r = 0; r < 4; ++r)
        red[wr][wc][mi*16 + g*4 + r] = part[mi][r];
  }
  __syncthreads();
  if (tid < 128)
    spart[(size_t)blockIdx.y * (NB*TXD) + r0 + tid] =
        red[tid >> 6][0][tid & 63] + red[tid >> 6][1][tid & 63];
}

// ---------- softmax over Tx -> alphas [64, 1024] (4 column parts) ---------------
__global__ __launch_bounds__(256)
void softmax_tx(const float* __restrict__ spart, float* __restrict__ alphas)
{
  int n = blockIdx.x, tid = threadIdx.x;
  __shared__ float rb[4];
  __shared__ float sb[4];
  float v[4]; float mx = -1e30f;
  #pragma unroll
  for (int i = 0; i < 4; ++i) {
    int t = tid + i*256;
    float s = 0.f;
    #pragma unroll
    for (int p = 0; p < 4; ++p)
      s += spart[(size_t)p*(NB*TXD) + (size_t)n*TXD + t];
    v[i] = s;
    mx = fmaxf(mx, v[i]);
  }
  #pragma unroll
  for (int m = 32; m >= 1; m >>= 1) mx = fmaxf(mx, __shfl_xor(mx, m, 64));
  if ((tid & 63) == 0) rb[tid >> 6] = mx;
  __syncthreads();
  mx = fmaxf(fmaxf(rb[0], rb[1]), fmaxf(rb[2], rb[3]));
  float s = 0.f;
  #pragma unroll
  for (int i = 0; i < 4; ++i) { v[i] = __expf(v[i] - mx); s += v[i]; }
  #pragma unroll
  for (int m = 32; m >= 1; m >>= 1) s += __shfl_xor(s, m, 64);
  if ((tid & 63) == 0) sb[tid >> 6] = s;
  __syncthreads();
  s = sb[0] + sb[1] + sb[2] + sb[3];
  float inv = 1.0f / s;
  #pragma unroll
  for (int i = 0; i < 4; ++i) alphas[(size_t)n*TXD + tid + i*256] = v[i] * inv;
}

// ---------- context partial sums (16 chunks of 64 timesteps) --------------------
__global__ __launch_bounds__(512)
void context_partial(const float* __restrict__ enc, const float* __restrict__ alphas,
                     float* __restrict__ part)
{
  int n = blockIdx.y, chunk = blockIdx.x;
  int c = threadIdx.x;
  __shared__ float al[64];
  if (threadIdx.x < 64) al[threadIdx.x] = alphas[(size_t)n*TXD + chunk*64 + threadIdx.x];
  __syncthreads();
  const float* e = enc + ((size_t)n*TXD + chunk*64) * NHD + c;
  float s = 0.f;
  #pragma unroll 4
  for (int t = 0; t < 64; ++t) s = fmaf(al[t], e[(size_t)t * NHD], s);
  part[((size_t)n*16 + chunk) * NHD + c] = s;
}

// ---------- reduce context + build post concat [h0out | ctx | h1] ---------------
__global__ __launch_bounds__(256)
void finalize_context(const float* __restrict__ part, const float* __restrict__ h0out,
                      const float* __restrict__ h1in,
                      float* __restrict__ ctx_out, float* __restrict__ cat)
{
  int i = blockIdx.x * 256 + threadIdx.x;   // < 64*512
  int n = i >> 9, c = i & 511;
  float s = 0.f;
  #pragma unroll
  for (int j = 0; j < 16; ++j) s += part[((size_t)n*16 + j) * NHD + c];
  ctx_out[i] = s;
  cat[(size_t)n * KPOST + c] = h0out[i];
  cat[(size_t)n * KPOST + HSZ + c] = s;
  cat[(size_t)n * KPOST + 2*HSZ + c] = h1in[i];
}

// ---------- BN train-mode stats -> scale/shift ----------------------------------
__global__ __launch_bounds__(256)
void bn_stats(const float* __restrict__ z, const float* __restrict__ gamma,
              const float* __restrict__ beta, float* __restrict__ scale,
              float* __restrict__ shift)
{
  int v = blockIdx.x * 256 + threadIdx.x;
  if (v >= VSZ) return;
  float s = 0.f, s2 = 0.f;
  #pragma unroll 4
  for (int n = 0; n < NB; ++n) {
    float x = z[(size_t)n * VSZ + v];
    s += x; s2 = fmaf(x, x, s2);
  }
  float mean = s * (1.0f / NB);
  float var = s2 * (1.0f / NB) - mean * mean;
  float r = rsqrtf(var + 1e-5f);
  float sc = gamma[v] * r;
  scale[v] = sc;
  shift[v] = beta[v] - mean * sc;
}

// ---------- final softmax over V: z cached in registers (1 read pass) -----------
__global__ __launch_bounds__(1024)
void softmax_v(const float* __restrict__ z, const float* __restrict__ scale,
               const float* __restrict__ shift, float* __restrict__ out)
{
  int n = blockIdx.x, tid = threadIdx.x;
  const float* zr = z + (size_t)n * VSZ;
  float* orow = out + (size_t)n * VSZ;
  __shared__ float rb[16];
  __shared__ float sb[16];
  float v[32]; float mx = -1e30f;
  #pragma unroll
  for (int i = 0; i < 32; ++i) {
    int j = tid + i*1024;
    v[i] = (j < VSZ) ? fmaf(zr[j], scale[j], shift[j]) : -1e30f;
    mx = fmaxf(mx, v[i]);
  }
  #pragma unroll
  for (int m = 32; m >= 1; m >>= 1) mx = fmaxf(mx, __shfl_xor(mx, m, 64));
  if ((tid & 63) == 0) rb[tid >> 6] = mx;
  __syncthreads();
  #pragma unroll
  for (int i = 0; i < 16; ++i) mx = fmaxf(mx, rb[i]);
  float s = 0.f;
  #pragma unroll
  for (int i = 0; i < 32; ++i) { v[i] = __expf(v[i] - mx); s += v[i]; }
  #pragma unroll
  for (int m = 32; m >= 1; m >>= 1) s += __shfl_xor(s, m, 64);
  if ((tid & 63) == 0) sb[tid >> 6] = s;
  __syncthreads();
  s = 0.f;
  #pragma unroll
  for (int i = 0; i < 16; ++i) s += sb[i];
  float inv = 1.0f / s;
  #pragma unroll
  for (int i = 0; i < 32; ++i) {
    int j = tid + i*1024;
    if (j < VSZ) orow[j] = v[i] * inv;
  }
}

// =================================================================================
extern "C" void kernel_launch(void* const* d_in, const int* in_sizes, int n_in,
                              void* d_out, int out_size, void* d_ws, size_t ws_size,
                              hipStream_t stream)
{
  const int*   yt       = (const int*)  d_in[0];
  const float* h0       = (const float*)d_in[1];
  const float* c0       = (const float*)d_in[2];
  const float* h1       = (const float*)d_in[3];
  const float* c1       = (const float*)d_in[4];
  const float* enc      = (const float*)d_in[5];
  const float* c_prev   = (const float*)d_in[6];
  const float* embW     = (const float*)d_in[7];
  const float* pre_Wih  = (const float*)d_in[8];
  const float* pre_Whh  = (const float*)d_in[9];
  const float* pre_bih  = (const float*)d_in[10];
  const float* pre_bhh  = (const float*)d_in[11];
  const float* post_Wih = (const float*)d_in[12];
  const float* post_Whh = (const float*)d_in[13];
  const float* post_bih = (const float*)d_in[14];
  const float* post_bhh = (const float*)d_in[15];
  const float* att_W1   = (const float*)d_in[16];
  const float* att_b1   = (const float*)d_in[17];
  const float* att_W2   = (const float*)d_in[18];
  // d_in[19] = att_b2 cancels under softmax over Tx
  const float* mlp_W    = (const float*)d_in[20];
  const float* mlp_b    = (const float*)d_in[21];
  const float* bn_g     = (const float*)d_in[22];
  const float* bn_b     = (const float*)d_in[23];

  float* out   = (float*)d_out;
  float* o_h0  = out + (size_t)NB * VSZ;
  float* o_c0  = o_h0 + NB * HSZ;
  float* o_h1  = o_c0 + NB * HSZ;
  float* o_c1  = o_h1 + NB * HSZ;
  float* o_ctx = o_c1 + NB * HSZ;

  float* ws = (float*)d_ws;
  // Early region (steps 1-6); zbuf/bn (steps 7-8) overlay it — lifetimes disjoint.
  float* pre_cat  = ws;                               // 84,736
  float* gatesp   = ws + 84736;                       // 9*131,072 -> ends 1,264,384
  float* sprojp   = ws + 1264384;                     // 131,072
  float* spart    = ws + 1395456;                     // 4*65,536
  float* alphas   = ws + 1657600;                     // 65,536
  float* ctxp     = ws + 1723136;                     // 524,288 -> 2,247,424
  float* post_cat = ws + 2247424;                     // 98,304  -> 2,345,728
  float* zbuf     = ws;                               // 2,048,000 (overlay, step 7+)
  float* bnsc     = ws + 2048000;                     // 32,000
  float* bnsh     = ws + 2080000;                     // 32,000 (< 2,247,424: only overlays dead bufs)

  // 1. pre concat [emb | c_prev | h0]
  build_pre_cat<<<(NB*KPRE + 255)/256, 256, 0, stream>>>(yt, embW, c_prev, h0, pre_cat);
  // 2. pre gates (fused ih+hh, split-K x9, Kslice 160) + LSTM pointwise
  mfma_gemm<0><<<dim3(G4/256, 9), 256, 0, stream>>>(
      pre_cat, KPRE, KPRE, pre_Wih, ESZ + NHD, ESZ + NHD, pre_Whh, HSZ,
      nullptr, gatesp, G4, 160);
  lstm_point2<<<NB*HSZ/256, 256, 0, stream>>>(gatesp, 9, pre_bih, pre_bhh, c0, o_h0, o_c0);
  // 3. sproj partials: s_i @ W1_s^T (split-K x4)
  mfma_gemm<0><<<dim3(HALFD/256, 4), 256, 0, stream>>>(
      o_h0, HSZ, HSZ, att_W1 + NHD, NHD + HSZ, HSZ, att_W1 + NHD, NHD + HSZ,
      nullptr, sprojp, HALFD, 128);
  // 4. attention scores + softmax over Tx
  att_score<<<dim3(NB*TXD/128, 4), 256, 0, stream>>>(enc, att_W1, att_W2, sprojp, att_b1, spart);
  softmax_tx<<<NB, 256, 0, stream>>>(spart, alphas);
  // 5. context
  context_partial<<<dim3(16, NB), 512, 0, stream>>>(enc, alphas, ctxp);
  finalize_context<<<NB*NHD/256, 256, 0, stream>>>(ctxp, o_h0, h1, o_ctx, post_cat);
  // 6. post gates (fused ih+hh, split-K x8, Kslice 192) + LSTM pointwise
  mfma_gemm<0><<<dim3(G4/256, 8), 256, 0, stream>>>(
      post_cat, KPOST, KPOST, post_Wih, HSZ + NHD, HSZ + NHD, post_Whh, HSZ,
      nullptr, gatesp, G4, 192);
  lstm_point2<<<NB*HSZ/256, 256, 0, stream>>>(gatesp, 8, post_bih, post_bhh, c1, o_h1, o_c1);
  // 7. classifier z = relu(h1 @ mlp_W^T + b)
  mfma_gemm<3><<<dim3(VSZ/256, 1), 256, 0, stream>>>(
      o_h1, HSZ, HSZ, mlp_W, HSZ, HSZ, mlp_W, HSZ, mlp_b, zbuf, VSZ, 512);
  // 8. batchnorm (train stats) + softmax over V
  bn_stats<<<(VSZ + 255)/256, 256, 0, stream>>>(zbuf, bn_g, bn_b, bnsc, bnsh);
  softmax_v<<<NB, 1024, 0, stream>>>(zbuf, bnsc, bnsh, out);
}

// Round 4
// 181.530 us; speedup vs baseline: 2.5201x; 1.2568x over previous
//
#include <hip/hip_runtime.h>
#include <math.h>

#define DEVFN __device__ __forceinline__

typedef __attribute__((ext_vector_type(4))) float f32x4;
typedef __attribute__((ext_vector_type(8))) __bf16 bf16x8;
typedef __attribute__((ext_vector_type(8))) short short8v;

#define NB   64
#define TXD  1024
#define NHD  512
#define HSZ  512
#define ESZ  300
#define VSZ  32000
#define G4   (4*HSZ)           // 2048
#define KPRE (ESZ + NHD + HSZ) // 1324 (emb|c_prev|h0)
#define KPOST 1536             // (h0out|ctx|h1)
#define HALFD 512

DEVFN short f2bf(float f) {
  unsigned u = __float_as_uint(f);
  u = (u + 0x7fffu + ((u >> 16) & 1u)) >> 16;
  return (short)u;
}
DEVFN float sigm(float x) { return 1.0f / (1.0f + __expf(-x)); }

DEVFN short8v pack8(float4 a, float4 b) {
  short8v v;
  v[0]=f2bf(a.x); v[1]=f2bf(a.y); v[2]=f2bf(a.z); v[3]=f2bf(a.w);
  v[4]=f2bf(b.x); v[5]=f2bf(b.y); v[6]=f2bf(b.z); v[7]=f2bf(b.w);
  return v;
}
DEVFN bf16x8 pack8f(float4 a, float4 b) {
  bf16x8 v;
  v[0]=(__bf16)a.x; v[1]=(__bf16)a.y; v[2]=(__bf16)a.z; v[3]=(__bf16)a.w;
  v[4]=(__bf16)b.x; v[5]=(__bf16)b.y; v[6]=(__bf16)b.z; v[7]=(__bf16)b.w;
  return v;
}
// async global->LDS, 16B per lane: dest = uniform base + lane*16
DEVFN void gload16(const void* g, void* lds_base) {
  __builtin_amdgcn_global_load_lds(
      (const __attribute__((address_space(1))) unsigned int*)g,
      (__attribute__((address_space(3))) unsigned int*)lds_base, 16, 0, 0);
}

DEVFN float4 ldA4(const float* __restrict__ A, int lda, int row, int k, int Ka) {
  if (k >= Ka) { float4 z = {0.f,0.f,0.f,0.f}; return z; }
  return *(const float4*)(A + (size_t)row * lda + k);
}
DEVFN float4 ldB4(const float* __restrict__ B1, int ldb1, int split,
                  const float* __restrict__ B2, int ldb2, int row, int k, int Ka) {
  if (k >= Ka) { float4 z = {0.f,0.f,0.f,0.f}; return z; }
  if (k < split) return *(const float4*)(B1 + (size_t)row * ldb1 + k);
  return *(const float4*)(B2 + (size_t)row * ldb2 + (k - split));
}

// ---------- convert att_W1 enc-half to bf16 [512][512] --------------------------
__global__ __launch_bounds__(256)
void conv_w1(const float* __restrict__ W1, unsigned short* __restrict__ W1b)
{
  int i = blockIdx.x * 256 + threadIdx.x;     // 0..32767, 8 elems each
  int c = i >> 6, kq = (i & 63) * 8;
  float4 a = *(const float4*)(W1 + (size_t)c * 1024 + kq);
  float4 b = *(const float4*)(W1 + (size_t)c * 1024 + kq + 4);
  *(short8v*)(W1b + (size_t)c * 512 + kq) = pack8(a, b);
}

// ---------- build pre-LSTM concat input [emb | c_prev | h0]  (64 x 1324) --------
__global__ __launch_bounds__(256)
void build_pre_cat(const int* __restrict__ yt, const float* __restrict__ embW,
                   const float* __restrict__ c_prev, const float* __restrict__ h0,
                   float* __restrict__ cat)
{
  int i = blockIdx.x * 256 + threadIdx.x;   // < 64*1324
  if (i >= NB * KPRE) return;
  int n = i / KPRE, c = i - n * KPRE;
  float v;
  if (c < ESZ)            v = embW[(size_t)yt[n] * ESZ + c];
  else if (c < ESZ + NHD) v = c_prev[(size_t)n * NHD + (c - ESZ)];
  else                    v = h0[(size_t)n * HSZ + (c - ESZ - NHD)];
  cat[i] = v;
}

// ---------- generic MFMA GEMM, 128-col tiles: C[64 x N] = A[64 x K] B[N x K]^T --
// Kslice multiple of 32. Split-K partial at C + ks*64*ldc. EPI: 0 none, 3 relu+b.
template<int EPI>
__global__ __launch_bounds__(256)
void mfma_gemm128(const float* __restrict__ A, int lda, int Ka,
                  const float* __restrict__ B1, int ldb1, int split,
                  const float* __restrict__ B2, int ldb2,
                  const float* __restrict__ bias1,
                  float* __restrict__ C, int ldc, int Kslice)
{
  __shared__ __align__(16) short As[64][40];
  __shared__ __align__(16) short Bs[128][40];
  const int tid = threadIdx.x;
  const int w = tid >> 6, lane = tid & 63;
  const int wr = w >> 1, wc = w & 1;
  const int cl = lane & 15, g = lane >> 4;
  const int n0 = blockIdx.x * 128;
  const int ks = blockIdx.y;
  const int kbeg = ks * Kslice;
  const int kend = min(kbeg + Kslice, Ka);
  C += (size_t)ks * 64 * ldc;

  const f32x4 fz = {0.f,0.f,0.f,0.f};
  f32x4 acc[2][4];
  #pragma unroll
  for (int i = 0; i < 2; ++i)
    #pragma unroll
    for (int j = 0; j < 4; ++j) acc[i][j] = fz;

  const int sr  = tid >> 2;        // 0..63
  const int skc = (tid & 3) * 8;   // 0,8,16,24

  float4 ra0, ra1, rb0[2], rb1[2];
  // prologue load
  ra0 = ldA4(A, lda, sr, kbeg + skc, Ka);
  ra1 = ldA4(A, lda, sr, kbeg + skc + 4, Ka);
  #pragma unroll
  for (int it = 0; it < 2; ++it) {
    rb0[it] = ldB4(B1, ldb1, split, B2, ldb2, n0 + sr + it*64, kbeg + skc, Ka);
    rb1[it] = ldB4(B1, ldb1, split, B2, ldb2, n0 + sr + it*64, kbeg + skc + 4, Ka);
  }

  for (int k0 = kbeg; k0 < kend; k0 += 32) {
    __syncthreads();
    *(short8v*)&As[sr][skc] = pack8(ra0, ra1);
    #pragma unroll
    for (int it = 0; it < 2; ++it)
      *(short8v*)&Bs[sr + it*64][skc] = pack8(rb0[it], rb1[it]);
    __syncthreads();
    if (k0 + 32 < kend) {
      ra0 = ldA4(A, lda, sr, k0 + 32 + skc, Ka);
      ra1 = ldA4(A, lda, sr, k0 + 32 + skc + 4, Ka);
      #pragma unroll
      for (int it = 0; it < 2; ++it) {
        rb0[it] = ldB4(B1, ldb1, split, B2, ldb2, n0 + sr + it*64, k0 + 32 + skc, Ka);
        rb1[it] = ldB4(B1, ldb1, split, B2, ldb2, n0 + sr + it*64, k0 + 32 + skc + 4, Ka);
      }
    }
    bf16x8 af[2], bfr[4];
    #pragma unroll
    for (int mi = 0; mi < 2; ++mi)
      af[mi] = *(const bf16x8*)&As[wr*32 + mi*16 + cl][g * 8];
    #pragma unroll
    for (int ni = 0; ni < 4; ++ni)
      bfr[ni] = *(const bf16x8*)&Bs[wc*64 + ni*16 + cl][g * 8];
    #pragma unroll
    for (int mi = 0; mi < 2; ++mi)
      #pragma unroll
      for (int ni = 0; ni < 4; ++ni)
        acc[mi][ni] = __builtin_amdgcn_mfma_f32_16x16x32_bf16(af[mi], bfr[ni], acc[mi][ni], 0, 0, 0);
  }

  #pragma unroll
  for (int ni = 0; ni < 4; ++ni) {
    int nn = n0 + wc*64 + ni*16 + cl;
    float b = (EPI == 3) ? bias1[nn] : 0.f;
    #pragma unroll
    for (int mi = 0; mi < 2; ++mi)
      #pragma unroll
      for (int r = 0; r < 4; ++r) {
        int m = wr*32 + mi*16 + g*4 + r;
        float v = acc[mi][ni][r];
        if (EPI == 3) v = fmaxf(v + b, 0.f);
        C[(size_t)m * ldc + nn] = v;
      }
  }
}

// ---------- LSTM pointwise, summing np split-K gate partials --------------------
__global__ __launch_bounds__(256)
void lstm_point2(const float* __restrict__ gp, int np,
                 const float* __restrict__ bih, const float* __restrict__ bhh,
                 const float* __restrict__ c_old,
                 float* __restrict__ h_new, float* __restrict__ c_new)
{
  int i = blockIdx.x * 256 + threadIdx.x;   // < 64*512
  int n = i >> 9, k = i & 511;
  float g[4];
  #pragma unroll
  for (int j = 0; j < 4; ++j) {
    int idx = j * 512 + k;
    float s = bih[idx] + bhh[idx];
    for (int ks = 0; ks < np; ++ks)
      s += gp[((size_t)ks*64 + n) * G4 + idx];
    g[j] = s;
  }
  float c = sigm(g[1]) * c_old[i] + sigm(g[0]) * tanhf(g[2]);
  float h = sigm(g[3]) * tanhf(c);
  h_new[i] = h; c_new[i] = c;
}

// ---------- attention scores: 128 rows x ALL 512 cols per block -----------------
// 8 waves (2 row x 4 col), double-buffered global_load_lds staging.
// A: enc f32 in LDS, swizzle phys_slot16 = logical ^ (row&7); bf16 at frag build.
// B: W1b bf16 in LDS, swizzle phys_slot16 = logical ^ (row&3).
__global__ __launch_bounds__(512)
void att_score8(const float* __restrict__ enc, const unsigned short* __restrict__ W1b,
                const float* __restrict__ W2, const float* __restrict__ sprojp,
                const float* __restrict__ b1, float* __restrict__ spart)
{
  __shared__ __align__(16) float As[2][128][32];           // 2 x 16 KB
  __shared__ __align__(16) unsigned short Bs[2][512][32];  // 2 x 32 KB
  __shared__ float red[2][4][64];
  const int tid = threadIdx.x;
  const int wid = tid >> 6, lane = tid & 63;
  const int wr = wid >> 2, wc = wid & 3;
  const int cl = lane & 15, g = lane >> 4;
  const int r0 = blockIdx.x * 128;
  const int n = r0 >> 10;

  // swizzled per-lane source offsets (gload_lds writes linearly: row=lane/slots)
  const int arow = lane >> 3;                       // 0..7   (A: 8 rows/call)
  const int acol = ((lane & 7) ^ arow) << 2;        // f32 units
  const int brow = lane >> 2;                       // 0..15  (B: 16 rows/call)
  const int bcol = ((lane & 3) ^ (brow & 3)) << 3;  // bf16 units

  const f32x4 fz = {0.f,0.f,0.f,0.f};
  f32x4 acc[4][8];
  #pragma unroll
  for (int mi = 0; mi < 4; ++mi)
    #pragma unroll
    for (int ni = 0; ni < 8; ++ni) acc[mi][ni] = fz;

  #define STAGE(buf, t) do {                                                   \
    int k0 = (t) * 32;                                                         \
    _Pragma("unroll")                                                          \
    for (int j2 = 0; j2 < 2; ++j2) {                                           \
      int j = wid * 2 + j2;                                                    \
      gload16(enc + (size_t)(r0 + j*8 + arow) * 512 + k0 + acol,               \
              &As[buf][j*8][0]);                                               \
    }                                                                          \
    _Pragma("unroll")                                                          \
    for (int j4 = 0; j4 < 4; ++j4) {                                           \
      int j = wid * 4 + j4;                                                    \
      gload16(W1b + (size_t)(j*16 + brow) * 512 + k0 + bcol,                   \
              &Bs[buf][j*16][0]);                                              \
    }                                                                          \
  } while (0)

  STAGE(0, 0);
  __syncthreads();
  for (int t = 0; t < 16; ++t) {
    const int cur = t & 1;
    if (t < 15) STAGE(cur ^ 1, t + 1);
    // compute on buffer cur
    bf16x8 af[4];
    #pragma unroll
    for (int mi = 0; mi < 4; ++mi) {
      int row = wr*64 + mi*16 + cl;
      const char* rp = (const char*)&As[cur][0][0] + (size_t)row * 128;
      float4 lo = *(const float4*)(rp + ((((g<<1)    ) ^ (cl & 7)) << 4));
      float4 hi = *(const float4*)(rp + ((((g<<1) + 1) ^ (cl & 7)) << 4));
      af[mi] = pack8f(lo, hi);
    }
    #pragma unroll
    for (int ni = 0; ni < 8; ++ni) {
      int row = wc*128 + ni*16 + cl;
      bf16x8 bf = *(const bf16x8*)((const char*)&Bs[cur][0][0] + (size_t)row * 64
                                   + ((g ^ (cl & 3)) << 4));
      #pragma unroll
      for (int mi = 0; mi < 4; ++mi)
        acc[mi][ni] = __builtin_amdgcn_mfma_f32_16x16x32_bf16(af[mi], bf, acc[mi][ni], 0, 0, 0);
    }
    __syncthreads();
  }
  #undef STAGE

  // epilogue: relu(acc + sproj + b1) * W2, reduce over this wave's 128 cols
  float part[4][4] = {};
  #pragma unroll
  for (int ni = 0; ni < 8; ++ni) {
    int c = wc*128 + ni*16 + cl;
    float spv = b1[c];
    #pragma unroll
    for (int ks = 0; ks < 4; ++ks)
      spv += sprojp[((size_t)ks*64 + n) * HALFD + c];
    float w2 = W2[c];
    #pragma unroll
    for (int mi = 0; mi < 4; ++mi)
      #pragma unroll
      for (int r = 0; r < 4; ++r)
        part[mi][r] += fmaxf(acc[mi][ni][r] + spv, 0.f) * w2;
  }
  #pragma unroll
  for (int mm = 1; mm < 16; mm <<= 1)
    #pragma unroll
    for (int mi = 0; mi < 4; ++mi)
      #pragma unroll
      for (int r = 0; r < 4; ++r)
        part[mi][r] += __shfl_xor(part[mi][r], mm, 64);
  if (cl == 0) {
    #pragma unroll
    for (int mi = 0; mi < 4; ++mi)
      #pragma unroll
      for (int r = 0; r < 4; ++r)
        red[wr][wc][mi*16 + g*4 + r] = part[mi][r];
  }
  __syncthreads();
  if (tid < 128) {
    float s = red[tid>>6][0][tid&63] + red[tid>>6][1][tid&63]
            + red[tid>>6][2][tid&63] + red[tid>>6][3][tid&63];
    spart[(size_t)r0 + tid] = s;
  }
}

// ---------- softmax over Tx -> alphas [64, 1024] --------------------------------
__global__ __launch_bounds__(256)
void softmax_tx(const float* __restrict__ spart, float* __restrict__ alphas)
{
  int n = blockIdx.x, tid = threadIdx.x;
  __shared__ float rb[4];
  __shared__ float sb[4];
  float v[4]; float mx = -1e30f;
  #pragma unroll
  for (int i = 0; i < 4; ++i) {
    v[i] = spart[(size_t)n*TXD + tid + i*256];
    mx = fmaxf(mx, v[i]);
  }
  #pragma unroll
  for (int m = 32; m >= 1; m >>= 1) mx = fmaxf(mx, __shfl_xor(mx, m, 64));
  if ((tid & 63) == 0) rb[tid >> 6] = mx;
  __syncthreads();
  mx = fmaxf(fmaxf(rb[0], rb[1]), fmaxf(rb[2], rb[3]));
  float s = 0.f;
  #pragma unroll
  for (int i = 0; i < 4; ++i) { v[i] = __expf(v[i] - mx); s += v[i]; }
  #pragma unroll
  for (int m = 32; m >= 1; m >>= 1) s += __shfl_xor(s, m, 64);
  if ((tid & 63) == 0) sb[tid >> 6] = s;
  __syncthreads();
  s = sb[0] + sb[1] + sb[2] + sb[3];
  float inv = 1.0f / s;
  #pragma unroll
  for (int i = 0; i < 4; ++i) alphas[(size_t)n*TXD + tid + i*256] = v[i] * inv;
}

// ---------- context partial sums (16 chunks of 64 timesteps) --------------------
__global__ __launch_bounds__(512)
void context_partial(const float* __restrict__ enc, const float* __restrict__ alphas,
                     float* __restrict__ part)
{
  int n = blockIdx.y, chunk = blockIdx.x;
  int c = threadIdx.x;
  __shared__ float al[64];
  if (threadIdx.x < 64) al[threadIdx.x] = alphas[(size_t)n*TXD + chunk*64 + threadIdx.x];
  __syncthreads();
  const float* e = enc + ((size_t)n*TXD + chunk*64) * NHD + c;
  float s = 0.f;
  #pragma unroll 4
  for (int t = 0; t < 64; ++t) s = fmaf(al[t], e[(size_t)t * NHD], s);
  part[((size_t)n*16 + chunk) * NHD + c] = s;
}

// ---------- reduce context + build post concat [h0out | ctx | h1] ---------------
__global__ __launch_bounds__(256)
void finalize_context(const float* __restrict__ part, const float* __restrict__ h0out,
                      const float* __restrict__ h1in,
                      float* __restrict__ ctx_out, float* __restrict__ cat)
{
  int i = blockIdx.x * 256 + threadIdx.x;   // < 64*512
  int n = i >> 9, c = i & 511;
  float s = 0.f;
  #pragma unroll
  for (int j = 0; j < 16; ++j) s += part[((size_t)n*16 + j) * NHD + c];
  ctx_out[i] = s;
  cat[(size_t)n * KPOST + c] = h0out[i];
  cat[(size_t)n * KPOST + HSZ + c] = s;
  cat[(size_t)n * KPOST + 2*HSZ + c] = h1in[i];
}

// ---------- BN train-mode stats -> scale/shift ----------------------------------
__global__ __launch_bounds__(256)
void bn_stats(const float* __restrict__ z, const float* __restrict__ gamma,
              const float* __restrict__ beta, float* __restrict__ scale,
              float* __restrict__ shift)
{
  int v = blockIdx.x * 256 + threadIdx.x;
  if (v >= VSZ) return;
  float s = 0.f, s2 = 0.f;
  #pragma unroll 4
  for (int n = 0; n < NB; ++n) {
    float x = z[(size_t)n * VSZ + v];
    s += x; s2 = fmaf(x, x, s2);
  }
  float mean = s * (1.0f / NB);
  float var = s2 * (1.0f / NB) - mean * mean;
  float r = rsqrtf(var + 1e-5f);
  float sc = gamma[v] * r;
  scale[v] = sc;
  shift[v] = beta[v] - mean * sc;
}

// ---------- final softmax over V: z cached in registers (1 read pass) -----------
__global__ __launch_bounds__(1024)
void softmax_v(const float* __restrict__ z, const float* __restrict__ scale,
               const float* __restrict__ shift, float* __restrict__ out)
{
  int n = blockIdx.x, tid = threadIdx.x;
  const float* zr = z + (size_t)n * VSZ;
  float* orow = out + (size_t)n * VSZ;
  __shared__ float rb[16];
  __shared__ float sb[16];
  float v[32]; float mx = -1e30f;
  #pragma unroll
  for (int i = 0; i < 32; ++i) {
    int j = tid + i*1024;
    v[i] = (j < VSZ) ? fmaf(zr[j], scale[j], shift[j]) : -1e30f;
    mx = fmaxf(mx, v[i]);
  }
  #pragma unroll
  for (int m = 32; m >= 1; m >>= 1) mx = fmaxf(mx, __shfl_xor(mx, m, 64));
  if ((tid & 63) == 0) rb[tid >> 6] = mx;
  __syncthreads();
  #pragma unroll
  for (int i = 0; i < 16; ++i) mx = fmaxf(mx, rb[i]);
  float s = 0.f;
  #pragma unroll
  for (int i = 0; i < 32; ++i) { v[i] = __expf(v[i] - mx); s += v[i]; }
  #pragma unroll
  for (int m = 32; m >= 1; m >>= 1) s += __shfl_xor(s, m, 64);
  if ((tid & 63) == 0) sb[tid >> 6] = s;
  __syncthreads();
  s = 0.f;
  #pragma unroll
  for (int i = 0; i < 16; ++i) s += sb[i];
  float inv = 1.0f / s;
  #pragma unroll
  for (int i = 0; i < 32; ++i) {
    int j = tid + i*1024;
    if (j < VSZ) orow[j] = v[i] * inv;
  }
}

// =================================================================================
extern "C" void kernel_launch(void* const* d_in, const int* in_sizes, int n_in,
                              void* d_out, int out_size, void* d_ws, size_t ws_size,
                              hipStream_t stream)
{
  const int*   yt       = (const int*)  d_in[0];
  const float* h0       = (const float*)d_in[1];
  const float* c0       = (const float*)d_in[2];
  const float* h1       = (const float*)d_in[3];
  const float* c1       = (const float*)d_in[4];
  const float* enc      = (const float*)d_in[5];
  const float* c_prev   = (const float*)d_in[6];
  const float* embW     = (const float*)d_in[7];
  const float* pre_Wih  = (const float*)d_in[8];
  const float* pre_Whh  = (const float*)d_in[9];
  const float* pre_bih  = (const float*)d_in[10];
  const float* pre_bhh  = (const float*)d_in[11];
  const float* post_Wih = (const float*)d_in[12];
  const float* post_Whh = (const float*)d_in[13];
  const float* post_bih = (const float*)d_in[14];
  const float* post_bhh = (const float*)d_in[15];
  const float* att_W1   = (const float*)d_in[16];
  const float* att_b1   = (const float*)d_in[17];
  const float* att_W2   = (const float*)d_in[18];
  // d_in[19] = att_b2 cancels under softmax over Tx
  const float* mlp_W    = (const float*)d_in[20];
  const float* mlp_b    = (const float*)d_in[21];
  const float* bn_g     = (const float*)d_in[22];
  const float* bn_b     = (const float*)d_in[23];

  float* out   = (float*)d_out;
  float* o_h0  = out + (size_t)NB * VSZ;
  float* o_c0  = o_h0 + NB * HSZ;
  float* o_h1  = o_c0 + NB * HSZ;
  float* o_c1  = o_h1 + NB * HSZ;
  float* o_ctx = o_c1 + NB * HSZ;

  float* ws = (float*)d_ws;
  // early region (steps 1-6); zbuf (steps 7-8) overlays dead early buffers.
  float* pre_cat  = ws;                         // @0        84,736
  float* gatesp   = ws + 84736;                 // @84736    9*131072 -> 1,264,384
  float* sprojp   = ws + 1264384;               // @1264384  131,072  -> 1,395,456
  float* spart    = ws + 1395456;               // @1395456  65,536   -> 1,460,992
  float* alphas   = ws + 1460992;               // @1460992  65,536   -> 1,526,528
  float* ctxp     = ws + 1526528;               // @1526528  524,288  -> 2,050,816
  float* post_cat = ws + 2050816;               // @2050816  98,304   -> 2,149,120
  unsigned short* W1b = (unsigned short*)(ws + 2149120);  // 262,144 u16 -> 2,280,192
  float* zbuf     = ws;                         // @0 overlay, 2,048,000 (step 7+)
  float* bnsc     = ws + 2280192;               // 32,000
  float* bnsh     = ws + 2312192;               // 32,000 -> total 2,344,192 f (9.4 MB)

  // 0. W1 enc-half -> bf16 (tiny, L2-resident afterwards)
  conv_w1<<<128, 256, 0, stream>>>(att_W1, W1b);
  // 1. pre concat [emb | c_prev | h0]
  build_pre_cat<<<(NB*KPRE + 255)/256, 256, 0, stream>>>(yt, embW, c_prev, h0, pre_cat);
  // 2. pre gates (fused ih+hh, split-K x9) + LSTM pointwise
  mfma_gemm128<0><<<dim3(G4/128, 9), 256, 0, stream>>>(
      pre_cat, KPRE, KPRE, pre_Wih, ESZ + NHD, ESZ + NHD, pre_Whh, HSZ,
      nullptr, gatesp, G4, 160);
  lstm_point2<<<NB*HSZ/256, 256, 0, stream>>>(gatesp, 9, pre_bih, pre_bhh, c0, o_h0, o_c0);
  // 3. sproj partials: s_i @ W1_s^T (split-K x4)
  mfma_gemm128<0><<<dim3(HALFD/128, 4), 256, 0, stream>>>(
      o_h0, HSZ, HSZ, att_W1 + NHD, NHD + HSZ, HSZ, att_W1 + NHD, NHD + HSZ,
      nullptr, sprojp, HALFD, 128);
  // 4. attention scores (enc read exactly once) + softmax over Tx
  att_score8<<<NB*TXD/128, 512, 0, stream>>>(enc, W1b, att_W2, sprojp, att_b1, spart);
  softmax_tx<<<NB, 256, 0, stream>>>(spart, alphas);
  // 5. context
  context_partial<<<dim3(16, NB), 512, 0, stream>>>(enc, alphas, ctxp);
  finalize_context<<<NB*NHD/256, 256, 0, stream>>>(ctxp, o_h0, h1, o_ctx, post_cat);
  // 6. post gates (fused ih+hh, split-K x8) + LSTM pointwise
  mfma_gemm128<0><<<dim3(G4/128, 8), 256, 0, stream>>>(
      post_cat, KPOST, KPOST, post_Wih, HSZ + NHD, HSZ + NHD, post_Whh, HSZ,
      nullptr, gatesp, G4, 192);
  lstm_point2<<<NB*HSZ/256, 256, 0, stream>>>(gatesp, 8, post_bih, post_bhh, c1, o_h1, o_c1);
  // 7. classifier z = relu(h1 @ mlp_W^T + b)  (250 blocks -> full GPU)
  mfma_gemm128<3><<<dim3(VSZ/128, 1), 256, 0, stream>>>(
      o_h1, HSZ, HSZ, mlp_W, HSZ, HSZ, mlp_W, HSZ, mlp_b, zbuf, VSZ, 512);
  // 8. batchnorm (train stats) + softmax over V
  bn_stats<<<(VSZ + 255)/256, 256, 0, stream>>>(zbuf, bn_g, bn_b, bnsc, bnsh);
  softmax_v<<<NB, 1024, 0, stream>>>(zbuf, bnsc, bnsh, out);
}

// Round 5
// 164.481 us; speedup vs baseline: 2.7814x; 1.1037x over previous
//
#include <hip/hip_runtime.h>
#include <math.h>

#define DEVFN __device__ __forceinline__

typedef __attribute__((ext_vector_type(4))) float f32x4;
typedef __attribute__((ext_vector_type(8))) __bf16 bf16x8;
typedef __attribute__((ext_vector_type(8))) short short8v;

#define NB   64
#define TXD  1024
#define NHD  512
#define HSZ  512
#define ESZ  300
#define VSZ  32000
#define G4   (4*HSZ)           // 2048
#define KPRE (ESZ + NHD + HSZ) // 1324 (emb|c_prev|h0)
#define KPOST 1536             // (h0out|ctx|h1)
#define HALFD 512

DEVFN short f2bf(float f) {
  unsigned u = __float_as_uint(f);
  u = (u + 0x7fffu + ((u >> 16) & 1u)) >> 16;
  return (short)u;
}
DEVFN float sigm(float x) { return 1.0f / (1.0f + __expf(-x)); }

DEVFN short8v pack8(float4 a, float4 b) {
  short8v v;
  v[0]=f2bf(a.x); v[1]=f2bf(a.y); v[2]=f2bf(a.z); v[3]=f2bf(a.w);
  v[4]=f2bf(b.x); v[5]=f2bf(b.y); v[6]=f2bf(b.z); v[7]=f2bf(b.w);
  return v;
}
DEVFN bf16x8 pack8f(float4 a, float4 b) {
  bf16x8 v;
  v[0]=(__bf16)a.x; v[1]=(__bf16)a.y; v[2]=(__bf16)a.z; v[3]=(__bf16)a.w;
  v[4]=(__bf16)b.x; v[5]=(__bf16)b.y; v[6]=(__bf16)b.z; v[7]=(__bf16)b.w;
  return v;
}
// async global->LDS, 16B per lane: dest = uniform base + lane*16
DEVFN void gload16(const void* g, void* lds_base) {
  __builtin_amdgcn_global_load_lds(
      (const __attribute__((address_space(1))) unsigned int*)g,
      (__attribute__((address_space(3))) unsigned int*)lds_base, 16, 0, 0);
}

DEVFN float4 ldA4(const float* __restrict__ A, int lda, int row, int k, int Ka) {
  if (k >= Ka) { float4 z = {0.f,0.f,0.f,0.f}; return z; }
  return *(const float4*)(A + (size_t)row * lda + k);
}
DEVFN float4 ldB4(const float* __restrict__ B1, int ldb1, int split,
                  const float* __restrict__ B2, int ldb2, int row, int k, int Ka) {
  if (k >= Ka) { float4 z = {0.f,0.f,0.f,0.f}; return z; }
  if (k < split) return *(const float4*)(B1 + (size_t)row * ldb1 + k);
  return *(const float4*)(B2 + (size_t)row * ldb2 + (k - split));
}

// ---------- prep: conv W1-enc-half to bf16 (blocks 0..127) + pre concat ---------
__global__ __launch_bounds__(256)
void prep(const int* __restrict__ yt, const float* __restrict__ embW,
          const float* __restrict__ c_prev, const float* __restrict__ h0,
          const float* __restrict__ W1, unsigned short* __restrict__ W1b,
          float* __restrict__ cat)
{
  int b = blockIdx.x;
  if (b < 128) {
    int i = b * 256 + threadIdx.x;            // 0..32767, 8 elems each
    int c = i >> 6, kq = (i & 63) * 8;
    float4 a = *(const float4*)(W1 + (size_t)c * 1024 + kq);
    float4 bb = *(const float4*)(W1 + (size_t)c * 1024 + kq + 4);
    *(short8v*)(W1b + (size_t)c * 512 + kq) = pack8(a, bb);
  } else {
    int i = (b - 128) * 256 + threadIdx.x;    // < 64*1324
    if (i >= NB * KPRE) return;
    int n = i / KPRE, c = i - n * KPRE;
    float v;
    if (c < ESZ)            v = embW[(size_t)yt[n] * ESZ + c];
    else if (c < ESZ + NHD) v = c_prev[(size_t)n * NHD + (c - ESZ)];
    else                    v = h0[(size_t)n * HSZ + (c - ESZ - NHD)];
    cat[i] = v;
  }
}

// ---------- generic MFMA GEMM, 128-col tiles: C[64 x N] = A[64 x K] B[N x K]^T --
// Kslice multiple of 32. Split-K partial at C + ks*64*ldc. EPI: 0 none, 3 relu+b.
template<int EPI>
__global__ __launch_bounds__(256)
void mfma_gemm128(const float* __restrict__ A, int lda, int Ka,
                  const float* __restrict__ B1, int ldb1, int split,
                  const float* __restrict__ B2, int ldb2,
                  const float* __restrict__ bias1,
                  float* __restrict__ C, int ldc, int Kslice)
{
  __shared__ __align__(16) short As[64][40];
  __shared__ __align__(16) short Bs[128][40];
  const int tid = threadIdx.x;
  const int w = tid >> 6, lane = tid & 63;
  const int wr = w >> 1, wc = w & 1;
  const int cl = lane & 15, g = lane >> 4;
  const int n0 = blockIdx.x * 128;
  const int ks = blockIdx.y;
  const int kbeg = ks * Kslice;
  const int kend = min(kbeg + Kslice, Ka);
  C += (size_t)ks * 64 * ldc;

  const f32x4 fz = {0.f,0.f,0.f,0.f};
  f32x4 acc[2][4];
  #pragma unroll
  for (int i = 0; i < 2; ++i)
    #pragma unroll
    for (int j = 0; j < 4; ++j) acc[i][j] = fz;

  const int sr  = tid >> 2;        // 0..63
  const int skc = (tid & 3) * 8;   // 0,8,16,24

  float4 ra0, ra1, rb0[2], rb1[2];
  ra0 = ldA4(A, lda, sr, kbeg + skc, Ka);
  ra1 = ldA4(A, lda, sr, kbeg + skc + 4, Ka);
  #pragma unroll
  for (int it = 0; it < 2; ++it) {
    rb0[it] = ldB4(B1, ldb1, split, B2, ldb2, n0 + sr + it*64, kbeg + skc, Ka);
    rb1[it] = ldB4(B1, ldb1, split, B2, ldb2, n0 + sr + it*64, kbeg + skc + 4, Ka);
  }

  for (int k0 = kbeg; k0 < kend; k0 += 32) {
    __syncthreads();
    *(short8v*)&As[sr][skc] = pack8(ra0, ra1);
    #pragma unroll
    for (int it = 0; it < 2; ++it)
      *(short8v*)&Bs[sr + it*64][skc] = pack8(rb0[it], rb1[it]);
    __syncthreads();
    if (k0 + 32 < kend) {
      ra0 = ldA4(A, lda, sr, k0 + 32 + skc, Ka);
      ra1 = ldA4(A, lda, sr, k0 + 32 + skc + 4, Ka);
      #pragma unroll
      for (int it = 0; it < 2; ++it) {
        rb0[it] = ldB4(B1, ldb1, split, B2, ldb2, n0 + sr + it*64, k0 + 32 + skc, Ka);
        rb1[it] = ldB4(B1, ldb1, split, B2, ldb2, n0 + sr + it*64, k0 + 32 + skc + 4, Ka);
      }
    }
    bf16x8 af[2], bfr[4];
    #pragma unroll
    for (int mi = 0; mi < 2; ++mi)
      af[mi] = *(const bf16x8*)&As[wr*32 + mi*16 + cl][g * 8];
    #pragma unroll
    for (int ni = 0; ni < 4; ++ni)
      bfr[ni] = *(const bf16x8*)&Bs[wc*64 + ni*16 + cl][g * 8];
    #pragma unroll
    for (int mi = 0; mi < 2; ++mi)
      #pragma unroll
      for (int ni = 0; ni < 4; ++ni)
        acc[mi][ni] = __builtin_amdgcn_mfma_f32_16x16x32_bf16(af[mi], bfr[ni], acc[mi][ni], 0, 0, 0);
  }

  #pragma unroll
  for (int ni = 0; ni < 4; ++ni) {
    int nn = n0 + wc*64 + ni*16 + cl;
    float b = (EPI == 3) ? bias1[nn] : 0.f;
    #pragma unroll
    for (int mi = 0; mi < 2; ++mi)
      #pragma unroll
      for (int r = 0; r < 4; ++r) {
        int m = wr*32 + mi*16 + g*4 + r;
        float v = acc[mi][ni][r];
        if (EPI == 3) v = fmaxf(v + b, 0.f);
        C[(size_t)m * ldc + nn] = v;
      }
  }
}

// ---------- LSTM pointwise, summing np split-K gate partials --------------------
__global__ __launch_bounds__(256)
void lstm_point2(const float* __restrict__ gp, int np,
                 const float* __restrict__ bih, const float* __restrict__ bhh,
                 const float* __restrict__ c_old,
                 float* __restrict__ h_new, float* __restrict__ c_new)
{
  int i = blockIdx.x * 256 + threadIdx.x;   // < 64*512
  int n = i >> 9, k = i & 511;
  float g[4];
  #pragma unroll
  for (int j = 0; j < 4; ++j) {
    int idx = j * 512 + k;
    float s = bih[idx] + bhh[idx];
    for (int ks = 0; ks < np; ++ks)
      s += gp[((size_t)ks*64 + n) * G4 + idx];
    g[j] = s;
  }
  float c = sigm(g[1]) * c_old[i] + sigm(g[0]) * tanhf(g[2]);
  float h = sigm(g[3]) * tanhf(c);
  h_new[i] = h; c_new[i] = c;
}

// ---------- fused attention: scores (MFMA, counted-vmcnt pipeline) +
//            block-local softmax + context partial over own 128 rows ------------
// Per block: 128 enc rows of one n, all 512 hidden cols. 8 waves (2r x 4c).
// A LDS: [128][32] f32, phys slot16 = slot ^ (row&7).
// B LDS: 2 logical rows per 128B LDS row; phys slot16 = (g ^ ((r>>1)&3)).
__global__ __launch_bounds__(512)
void att_fused(const float* __restrict__ enc, const unsigned short* __restrict__ W1b,
               const float* __restrict__ W2, const float* __restrict__ sprojp,
               const float* __restrict__ b1,
               float* __restrict__ mbuf, float* __restrict__ sbuf,
               float* __restrict__ ctxp)
{
  __shared__ __align__(16) float As3[3*4096];           // 48 KB
  __shared__ __align__(16) unsigned short Bs3[3*16384]; // 96 KB
  __shared__ float sc[128];
  __shared__ float eV[128];
  __shared__ float msh[1];
  const int tid = threadIdx.x;
  const int wid = tid >> 6, lane = tid & 63;
  const int wr = wid >> 2, wc = wid & 3;
  const int cl = lane & 15, g = lane >> 4;
  const int r0 = blockIdx.x * 128;
  const int n = r0 >> 10;

  // per-lane pre-swizzled source offsets for linear gload16 destinations
  const int a_r = lane >> 3;                          // 0..7
  const int a_c = ((lane & 7) ^ a_r) << 2;            // f32 units
  const int b_r = ((lane >> 3) << 1) + ((lane >> 2) & 1);  // 0..15
  const int b_c = ((lane & 3) ^ ((lane >> 3) & 3)) << 3;   // bf16 units

  const f32x4 fz = {0.f,0.f,0.f,0.f};
  f32x4 acc[4][8];
  #pragma unroll
  for (int mi = 0; mi < 4; ++mi)
    #pragma unroll
    for (int ni = 0; ni < 8; ++ni) acc[mi][ni] = fz;

  #define STAGE(buf, t) do {                                              \
    int k0 = (t) * 32;                                                    \
    _Pragma("unroll")                                                     \
    for (int j2 = 0; j2 < 2; ++j2) {                                      \
      int j = (wid << 1) + j2;                                            \
      gload16(enc + (size_t)(r0 + (j << 3) + a_r) * 512 + k0 + a_c,       \
              As3 + (buf) * 4096 + (j << 8));                             \
    }                                                                     \
    _Pragma("unroll")                                                     \
    for (int j4 = 0; j4 < 4; ++j4) {                                      \
      int j = (wid << 2) + j4;                                            \
      gload16(W1b + (size_t)((j << 4) + b_r) * 512 + k0 + b_c,            \
              Bs3 + (buf) * 16384 + (j << 9));                            \
    }                                                                     \
  } while (0)

  STAGE(0, 0);
  STAGE(1, 1);
  for (int t = 0; t < 16; ++t) {
    const int cur = t % 3;
    if (t < 15) asm volatile("s_waitcnt vmcnt(6)" ::: "memory");
    else        asm volatile("s_waitcnt vmcnt(0)" ::: "memory");
    __builtin_amdgcn_s_barrier();
    __builtin_amdgcn_sched_barrier(0);
    if (t + 2 < 16) STAGE((t + 2) % 3, t + 2);
    const char* Ab = (const char*)(As3 + cur * 4096);
    const char* Bb = (const char*)(Bs3 + cur * 16384);
    bf16x8 af[4];
    #pragma unroll
    for (int mi = 0; mi < 4; ++mi) {
      int row = wr*64 + mi*16 + cl;
      float4 lo = *(const float4*)(Ab + row*128 + ((((g<<1)  ) ^ (cl & 7)) << 4));
      float4 hi = *(const float4*)(Ab + row*128 + ((((g<<1)|1) ^ (cl & 7)) << 4));
      af[mi] = pack8f(lo, hi);
    }
    #pragma unroll
    for (int ni = 0; ni < 8; ++ni) {
      int row = wc*128 + ni*16 + cl;
      bf16x8 bf = *(const bf16x8*)(Bb + (row >> 1)*128 + ((row & 1) << 6)
                                   + ((g ^ ((row >> 1) & 3)) << 4));
      #pragma unroll
      for (int mi = 0; mi < 4; ++mi)
        acc[mi][ni] = __builtin_amdgcn_mfma_f32_16x16x32_bf16(af[mi], bf, acc[mi][ni], 0, 0, 0);
    }
  }
  #undef STAGE
  __syncthreads();   // all waves done with LDS buffers

  // epilogue: relu(acc + sproj + b1) * W2, reduce over this wave's 128 cols
  float* red = (float*)Bs3;   // [8][64], aliases dead B staging
  float part[4][4] = {};
  #pragma unroll
  for (int ni = 0; ni < 8; ++ni) {
    int c = wc*128 + ni*16 + cl;
    float spv = b1[c];
    #pragma unroll
    for (int ks = 0; ks < 4; ++ks)
      spv += sprojp[((size_t)ks*64 + n) * HALFD + c];
    float w2 = W2[c];
    #pragma unroll
    for (int mi = 0; mi < 4; ++mi)
      #pragma unroll
      for (int r = 0; r < 4; ++r)
        part[mi][r] += fmaxf(acc[mi][ni][r] + spv, 0.f) * w2;
  }
  #pragma unroll
  for (int mm = 1; mm < 16; mm <<= 1)
    #pragma unroll
    for (int mi = 0; mi < 4; ++mi)
      #pragma unroll
      for (int r = 0; r < 4; ++r)
        part[mi][r] += __shfl_xor(part[mi][r], mm, 64);
  if (cl == 0) {
    #pragma unroll
    for (int mi = 0; mi < 4; ++mi)
      #pragma unroll
      for (int r = 0; r < 4; ++r)
        red[(wr*4 + wc)*64 + mi*16 + g*4 + r] = part[mi][r];
  }
  __syncthreads();
  if (tid < 128) {
    int h = tid >> 6, idx = tid & 63;
    sc[tid] = red[(h*4 + 0)*64 + idx] + red[(h*4 + 1)*64 + idx]
            + red[(h*4 + 2)*64 + idx] + red[(h*4 + 3)*64 + idx];
  }
  __syncthreads();
  // block-local max
  if (tid < 64) {
    float a = fmaxf(sc[tid], sc[tid + 64]);
    #pragma unroll
    for (int mm = 32; mm >= 1; mm >>= 1) a = fmaxf(a, __shfl_xor(a, mm, 64));
    if (tid == 0) msh[0] = a;
  }
  __syncthreads();
  const float M = msh[0];
  if (tid < 128) eV[tid] = __expf(sc[tid] - M);
  __syncthreads();
  if (tid < 64) {
    float a = eV[tid] + eV[tid + 64];
    #pragma unroll
    for (int mm = 32; mm >= 1; mm >>= 1) a += __shfl_xor(a, mm, 64);
    if (tid == 0) { mbuf[blockIdx.x] = M; sbuf[blockIdx.x] = a; }
  }

  // pass 2: ctx_b[c] = sum_t eV[t] * enc[r0+t][c]  (rows are L2-hot)
  f32x4* red4 = (f32x4*)As3;   // [4][128] float4, aliases dead A staging
  {
    const int cgrp = tid & 127, tq = tid >> 7;      // tq uniform per wave
    const float* ebase = enc + (size_t)r0 * 512 + (cgrp << 2);
    f32x4 a4 = fz;
    #pragma unroll 8
    for (int tt = 0; tt < 32; ++tt) {
      int t = tq*32 + tt;
      float et = eV[t];
      float4 x = *(const float4*)(ebase + (size_t)t * 512);
      a4[0] = fmaf(et, x.x, a4[0]);
      a4[1] = fmaf(et, x.y, a4[1]);
      a4[2] = fmaf(et, x.z, a4[2]);
      a4[3] = fmaf(et, x.w, a4[3]);
    }
    red4[tq*128 + cgrp] = a4;
  }
  __syncthreads();
  if (tid < 128) {
    f32x4 s4 = red4[tid] ;
    f32x4 b4 = red4[128 + tid];
    f32x4 c4 = red4[256 + tid];
    f32x4 d4 = red4[384 + tid];
    f32x4 o4;
    #pragma unroll
    for (int i = 0; i < 4; ++i) o4[i] = s4[i] + b4[i] + c4[i] + d4[i];
    *(f32x4*)(ctxp + (size_t)blockIdx.x * 512 + tid*4) = o4;
  }
}

// ---------- combine 8 block-partials per n -> context, post concat --------------
__global__ __launch_bounds__(256)
void att_combine(const float* __restrict__ mbuf, const float* __restrict__ sbuf,
                 const float* __restrict__ ctxp, const float* __restrict__ h0out,
                 const float* __restrict__ h1in,
                 float* __restrict__ ctx_out, float* __restrict__ cat)
{
  int i = blockIdx.x * 256 + threadIdx.x;   // < 64*512
  int n = i >> 9, c = i & 511;
  float m[8];
  float M = -1e30f;
  #pragma unroll
  for (int b = 0; b < 8; ++b) { m[b] = mbuf[n*8 + b]; M = fmaxf(M, m[b]); }
  float S = 0.f, ctx = 0.f;
  #pragma unroll
  for (int b = 0; b < 8; ++b) {
    float w = __expf(m[b] - M);
    S = fmaf(sbuf[n*8 + b], w, S);
    ctx = fmaf(ctxp[(size_t)(n*8 + b)*512 + c], w, ctx);
  }
  ctx /= S;
  ctx_out[i] = ctx;
  cat[(size_t)n * KPOST + c] = h0out[i];
  cat[(size_t)n * KPOST + HSZ + c] = ctx;
  cat[(size_t)n * KPOST + 2*HSZ + c] = h1in[i];
}

// ---------- BN train-mode stats -> scale/shift ----------------------------------
__global__ __launch_bounds__(256)
void bn_stats(const float* __restrict__ z, const float* __restrict__ gamma,
              const float* __restrict__ beta, float* __restrict__ scale,
              float* __restrict__ shift)
{
  int v = blockIdx.x * 256 + threadIdx.x;
  if (v >= VSZ) return;
  float s = 0.f, s2 = 0.f;
  #pragma unroll 4
  for (int n = 0; n < NB; ++n) {
    float x = z[(size_t)n * VSZ + v];
    s += x; s2 = fmaf(x, x, s2);
  }
  float mean = s * (1.0f / NB);
  float var = s2 * (1.0f / NB) - mean * mean;
  float r = rsqrtf(var + 1e-5f);
  float sc = gamma[v] * r;
  scale[v] = sc;
  shift[v] = beta[v] - mean * sc;
}

// ---------- final softmax over V: z cached in registers (1 read pass) -----------
__global__ __launch_bounds__(1024)
void softmax_v(const float* __restrict__ z, const float* __restrict__ scale,
               const float* __restrict__ shift, float* __restrict__ out)
{
  int n = blockIdx.x, tid = threadIdx.x;
  const float* zr = z + (size_t)n * VSZ;
  float* orow = out + (size_t)n * VSZ;
  __shared__ float rb[16];
  __shared__ float sb[16];
  float v[32]; float mx = -1e30f;
  #pragma unroll
  for (int i = 0; i < 32; ++i) {
    int j = tid + i*1024;
    v[i] = (j < VSZ) ? fmaf(zr[j], scale[j], shift[j]) : -1e30f;
    mx = fmaxf(mx, v[i]);
  }
  #pragma unroll
  for (int m = 32; m >= 1; m >>= 1) mx = fmaxf(mx, __shfl_xor(mx, m, 64));
  if ((tid & 63) == 0) rb[tid >> 6] = mx;
  __syncthreads();
  #pragma unroll
  for (int i = 0; i < 16; ++i) mx = fmaxf(mx, rb[i]);
  float s = 0.f;
  #pragma unroll
  for (int i = 0; i < 32; ++i) { v[i] = __expf(v[i] - mx); s += v[i]; }
  #pragma unroll
  for (int m = 32; m >= 1; m >>= 1) s += __shfl_xor(s, m, 64);
  if ((tid & 63) == 0) sb[tid >> 6] = s;
  __syncthreads();
  s = 0.f;
  #pragma unroll
  for (int i = 0; i < 16; ++i) s += sb[i];
  float inv = 1.0f / s;
  #pragma unroll
  for (int i = 0; i < 32; ++i) {
    int j = tid + i*1024;
    if (j < VSZ) orow[j] = v[i] * inv;
  }
}

// =================================================================================
extern "C" void kernel_launch(void* const* d_in, const int* in_sizes, int n_in,
                              void* d_out, int out_size, void* d_ws, size_t ws_size,
                              hipStream_t stream)
{
  const int*   yt       = (const int*)  d_in[0];
  const float* h0       = (const float*)d_in[1];
  const float* c0       = (const float*)d_in[2];
  const float* h1       = (const float*)d_in[3];
  const float* c1       = (const float*)d_in[4];
  const float* enc      = (const float*)d_in[5];
  const float* c_prev   = (const float*)d_in[6];
  const float* embW     = (const float*)d_in[7];
  const float* pre_Wih  = (const float*)d_in[8];
  const float* pre_Whh  = (const float*)d_in[9];
  const float* pre_bih  = (const float*)d_in[10];
  const float* pre_bhh  = (const float*)d_in[11];
  const float* post_Wih = (const float*)d_in[12];
  const float* post_Whh = (const float*)d_in[13];
  const float* post_bih = (const float*)d_in[14];
  const float* post_bhh = (const float*)d_in[15];
  const float* att_W1   = (const float*)d_in[16];
  const float* att_b1   = (const float*)d_in[17];
  const float* att_W2   = (const float*)d_in[18];
  // d_in[19] = att_b2 cancels under softmax over Tx
  const float* mlp_W    = (const float*)d_in[20];
  const float* mlp_b    = (const float*)d_in[21];
  const float* bn_g     = (const float*)d_in[22];
  const float* bn_b     = (const float*)d_in[23];

  float* out   = (float*)d_out;
  float* o_h0  = out + (size_t)NB * VSZ;
  float* o_c0  = o_h0 + NB * HSZ;
  float* o_h1  = o_c0 + NB * HSZ;
  float* o_c1  = o_h1 + NB * HSZ;
  float* o_ctx = o_c1 + NB * HSZ;

  float* ws = (float*)d_ws;
  // early region (steps 1-6); zbuf (steps 7-8) overlays dead early buffers.
  float* pre_cat  = ws;                         // @0          84,736
  float* gatesp   = ws + 84736;                 // @84,736     9*131,072 -> 1,264,384
  float* sprojp   = ws + 1264384;               // @1,264,384  131,072   -> 1,395,456
  float* mbuf     = ws + 1395456;               // 512
  float* sbuf     = ws + 1395968;               // 512       -> 1,396,480
  float* ctxp     = ws + 1396480;               // 262,144   -> 1,658,624
  float* post_cat = ws + 1658624;               // 98,304    -> 1,756,928
  unsigned short* W1b = (unsigned short*)(ws + 1756928);  // 262,144 u16 -> 1,888,000
  float* zbuf     = ws;                         // @0 overlay, 2,048,000 (step 7+)
  float* bnsc     = ws + 2048000;               // 32,000
  float* bnsh     = ws + 2080000;               // 32,000 -> 2,112,000 f (8.45 MB)

  // 1. prep: W1->bf16 + pre concat [emb | c_prev | h0]
  prep<<<128 + (NB*KPRE + 255)/256, 256, 0, stream>>>(yt, embW, c_prev, h0,
                                                      att_W1, W1b, pre_cat);
  // 2. pre gates (fused ih+hh, split-K x9) + LSTM pointwise
  mfma_gemm128<0><<<dim3(G4/128, 9), 256, 0, stream>>>(
      pre_cat, KPRE, KPRE, pre_Wih, ESZ + NHD, ESZ + NHD, pre_Whh, HSZ,
      nullptr, gatesp, G4, 160);
  lstm_point2<<<NB*HSZ/256, 256, 0, stream>>>(gatesp, 9, pre_bih, pre_bhh, c0, o_h0, o_c0);
  // 3. sproj partials: s_i @ W1_s^T (split-K x4)
  mfma_gemm128<0><<<dim3(HALFD/128, 4), 256, 0, stream>>>(
      o_h0, HSZ, HSZ, att_W1 + NHD, NHD + HSZ, HSZ, att_W1 + NHD, NHD + HSZ,
      nullptr, sprojp, HALFD, 128);
  // 4. fused attention (scores + block softmax + context partials) + combine
  att_fused<<<NB*TXD/128, 512, 0, stream>>>(enc, W1b, att_W2, sprojp, att_b1,
                                            mbuf, sbuf, ctxp);
  att_combine<<<NB*NHD/256, 256, 0, stream>>>(mbuf, sbuf, ctxp, o_h0, h1, o_ctx, post_cat);
  // 5. post gates (fused ih+hh, split-K x8) + LSTM pointwise
  mfma_gemm128<0><<<dim3(G4/128, 8), 256, 0, stream>>>(
      post_cat, KPOST, KPOST, post_Wih, HSZ + NHD, HSZ + NHD, post_Whh, HSZ,
      nullptr, gatesp, G4, 192);
  lstm_point2<<<NB*HSZ/256, 256, 0, stream>>>(gatesp, 8, post_bih, post_bhh, c1, o_h1, o_c1);
  // 6. classifier z = relu(h1 @ mlp_W^T + b)
  mfma_gemm128<3><<<dim3(VSZ/128, 1), 256, 0, stream>>>(
      o_h1, HSZ, HSZ, mlp_W, HSZ, HSZ, mlp_W, HSZ, mlp_b, zbuf, VSZ, 512);
  // 7. batchnorm (train stats) + softmax over V
  bn_stats<<<(VSZ + 255)/256, 256, 0, stream>>>(zbuf, bn_g, bn_b, bnsc, bnsh);
  softmax_v<<<NB, 1024, 0, stream>>>(zbuf, bnsc, bnsh, out);
}